// Round 6
// baseline (1170.377 us; speedup 1.0000x reference)
//
#include <hip/hip_runtime.h>
#include <stdint.h>

#define NS   2048
#define NQ   6144
#define NN   8192      // total nodes
#define IND  512
#define DM   256
#define KNB  10

typedef short bf16x8 __attribute__((ext_vector_type(8)));
typedef float f32x4  __attribute__((ext_vector_type(4)));

// exact RNE fp32 -> bf16 (bits); bf16 exp range == fp32, no denormal hazard
__device__ __forceinline__ unsigned short f2bf(float v)
{
    unsigned int u = __float_as_uint(v);
    unsigned int r = (u + 0x7fffu + ((u >> 16) & 1u)) >> 16;
    return (unsigned short)r;
}
__device__ __forceinline__ float bf2f(unsigned short h)
{
    return __uint_as_float(((unsigned int)h) << 16);
}

// lexicographic (value, index) insert into sorted-ascending top-10 registers
__device__ __forceinline__ void topk_insert(float v, int j, float bval[KNB], int bidx[KNB])
{
    bool better = (v < bval[KNB-1]) || (v == bval[KNB-1] && j < bidx[KNB-1]);
    if (better) {
        float cv = v; int ci = j;
#pragma unroll
        for (int q = 0; q < KNB; ++q) {
            bool sw = (cv < bval[q]) || (cv == bval[q] && ci < bidx[q]);
            if (sw) {
                float tv = bval[q]; bval[q] = cv; cv = tv;
                int   ti = bidx[q]; bidx[q] = ci; ci = ti;
            }
        }
    }
}

// ---------- 1) embed: E = concat(support,query) @ W (8192x512x256), 64x128 tiles.
// Epilogue packs E into MFMA-fragment-ordered bf16 hi/lo arrays
//   G[c][node][q][j]  (c=k/32, q=(k>>3)&3, j=k&7; 16 B per (node,q))
// and writes per-row partial squared norms (exact fp32 from acc).
__global__ __launch_bounds__(256) void embed_kernel(
    const float* __restrict__ support, const float* __restrict__ query,
    const float* __restrict__ W, bf16x8* __restrict__ Ghi, bf16x8* __restrict__ Glo,
    float* __restrict__ sqpart)
{
    __shared__ float smemA[32 * 68];     // A^T: [k][m], 64 rows
    __shared__ float smemB[32 * 132];    // B:   [k][n], 128 cols
    __shared__ float sqred[64 * 17];
    const int t  = threadIdx.x;
    const int i0 = blockIdx.x * 64;
    const int n0 = blockIdx.y * 128;
    const int tx = t & 15, ty = t >> 4;

    float acc[4][8];
#pragma unroll
    for (int m = 0; m < 4; ++m)
#pragma unroll
        for (int n = 0; n < 8; ++n) acc[m][n] = 0.f;

    for (int kc = 0; kc < IND; kc += 32) {
        {
            int a  = t >> 2;            // 0..63
            int cg = (t & 3) * 8;       // 0,8,16,24
            int g  = i0 + a;
            const float* src = (g < NS) ? (support + (size_t)g * IND)
                                        : (query + (size_t)(g - NS) * IND);
            src += kc + cg;
#pragma unroll
            for (int q = 0; q < 2; ++q) {
                float4 v = *reinterpret_cast<const float4*>(src + q * 4);
                smemA[(cg + q*4 + 0) * 68 + a] = v.x;
                smemA[(cg + q*4 + 1) * 68 + a] = v.y;
                smemA[(cg + q*4 + 2) * 68 + a] = v.z;
                smemA[(cg + q*4 + 3) * 68 + a] = v.w;
            }
        }
        {
            int r  = t >> 3;            // 0..31
            int cg = (t & 7) * 16;      // 0..112
            const float* src = W + (size_t)(kc + r) * DM + n0 + cg;
#pragma unroll
            for (int q = 0; q < 4; ++q) {
                float4 v = *reinterpret_cast<const float4*>(src + q * 4);
                *reinterpret_cast<float4*>(&smemB[r * 132 + cg + q * 4]) = v;
            }
        }
        __syncthreads();
#pragma unroll
        for (int kk = 0; kk < 32; ++kk) {
            float4 a0 = *reinterpret_cast<const float4*>(&smemA[kk * 68 + ty * 4]);
            float4 b0 = *reinterpret_cast<const float4*>(&smemB[kk * 132 + tx * 8]);
            float4 b1 = *reinterpret_cast<const float4*>(&smemB[kk * 132 + tx * 8 + 4]);
            float af[4] = {a0.x, a0.y, a0.z, a0.w};
            float bf[8] = {b0.x, b0.y, b0.z, b0.w, b1.x, b1.y, b1.z, b1.w};
#pragma unroll
            for (int m = 0; m < 4; ++m)
#pragma unroll
                for (int n = 0; n < 8; ++n)
                    acc[m][n] += af[m] * bf[n];
        }
        __syncthreads();
    }
    // epilogue: pack hi/lo bf16 fragments + partial row norms
    const int cc = blockIdx.y * 4 + (tx >> 2);   // k-chunk
    const int qq = tx & 3;                       // quad within chunk
#pragma unroll
    for (int m = 0; m < 4; ++m) {
        int row = i0 + ty * 4 + m;
        bf16x8 h8, l8;
        float s = 0.f;
#pragma unroll
        for (int n = 0; n < 8; ++n) {
            float v = acc[m][n];
            unsigned short hu = f2bf(v);
            float hf = bf2f(hu);
            unsigned short lu = f2bf(v - hf);
            h8[n] = (short)hu;
            l8[n] = (short)lu;
            s += v * v;
        }
        size_t gi = ((size_t)cc * NN + row) * 4 + qq;
        Ghi[gi] = h8;
        Glo[gi] = l8;
        sqred[(ty * 4 + m) * 17 + tx] = s;
    }
    __syncthreads();
    if (t < 64) {
        float s = 0.f;
#pragma unroll
        for (int x = 0; x < 16; ++x) s += sqred[t * 17 + x];
        sqpart[(size_t)blockIdx.y * NN + i0 + t] = s;
    }
}

// ---------- 2) combine the two column-half partial norms ----------
__global__ __launch_bounds__(256) void sqsum_kernel(const float* __restrict__ sqpart,
                                                    float* __restrict__ sq)
{
    int i = blockIdx.x * 256 + threadIdx.x;
    sq[i] = sqpart[i] + sqpart[NN + i];
}

// ---------- 3) fused distance MFMA-GEMM + streaming per-row top-10 ----------
// bf16 2-way split (hi+lo), 4 MFMA products into fp32 acc (validated r5, absmax 0).
// Block 128x128, 4 waves in 2x2, wave tile 64x64.
// Epilogue is WAVE-PRIVATE and barrier-free: each wave stages its 64x64 quadrant
// into its own 64x33-float LDS patch in two 32-col halves and scans immediately
// (lane = row). Stride 33 -> scan bank=(lane+s)%32 = 2-way (free); store rotation
// p=(c+4q)&31 -> banks hit exactly 2x (free). Intra-wave LDS RAW needs only
// lgkmcnt (compiler-inserted) — NO __syncthreads in the main loop. LDS = 33792 B
// -> 4 blocks/CU; with nsplit=16 the grid is 1024 = 4/CU.
__global__ __launch_bounds__(256) void dist_topk_kernel(
    const bf16x8* __restrict__ Ghi, const bf16x8* __restrict__ Glo,
    const float* __restrict__ sq, float* __restrict__ cval, int* __restrict__ cidx,
    int nsplit, int cstride)
{
    __shared__ float smem[4][64 * 33];           // 33792 B, per-wave private
    const int t  = threadIdx.x;
    const int l  = t & 63, w = t >> 6;
    const int wr = w >> 1, wc = w & 1;
    const int lm = l & 15, q = l >> 4;
    const int i0 = blockIdx.x * 128;
    const int split = blockIdx.y;
    float* buf = smem[w];

    // hoisted row norms: acc reg r of m-tile mt maps to row 16*mt + 4*q + r
    f32x4 sqr[4];
#pragma unroll
    for (int mt = 0; mt < 4; ++mt)
        sqr[mt] = *reinterpret_cast<const f32x4*>(&sq[i0 + 64 * wr + 16 * mt + 4 * q]);

    const size_t aBase = (size_t)(i0 + 64 * wr + lm) * 4 + q;   // bf16x8 units
    const int    cb    = 64 * wc + lm;
    const int    qrow  = (l >> 2) & 3;           // (row%16)>>2 for row = l (scan side)

    float bval[KNB]; int bidx[KNB];
#pragma unroll
    for (int s = 0; s < KNB; ++s) { bval[s] = 3.0e38f; bidx[s] = 0x7fffffff; }
    float thr_v = 3.0e38f; int thr_i = 0x7fffffff;

    const int njt = 64 / nsplit;                 // 4 (nsplit=16) or 8
    for (int jt = split * njt; jt < split * njt + njt; ++jt) {
        const int j0 = jt * 128;
        const size_t bBase = (size_t)(j0 + cb) * 4 + q;

        f32x4 acc[4][4];
#pragma unroll
        for (int mt = 0; mt < 4; ++mt)
#pragma unroll
            for (int nt = 0; nt < 4; ++nt) acc[mt][nt] = (f32x4){0.f, 0.f, 0.f, 0.f};

        for (int c = 0; c < 8; ++c) {
            const size_t co = (size_t)c * (NN * 4);
            bf16x8 Ah[4], Al[4], Bh[4], Bl[4];
#pragma unroll
            for (int mt = 0; mt < 4; ++mt) {
                Ah[mt] = Ghi[aBase + co + mt * 64];
                Al[mt] = Glo[aBase + co + mt * 64];
            }
#pragma unroll
            for (int nt = 0; nt < 4; ++nt) {
                Bh[nt] = Ghi[bBase + co + nt * 64];
                Bl[nt] = Glo[bBase + co + nt * 64];
            }
#pragma unroll
            for (int mt = 0; mt < 4; ++mt)
#pragma unroll
                for (int nt = 0; nt < 4; ++nt) {
                    f32x4 a = acc[mt][nt];
                    a = __builtin_amdgcn_mfma_f32_16x16x32_bf16(Ah[mt], Bh[nt], a, 0, 0, 0);
                    a = __builtin_amdgcn_mfma_f32_16x16x32_bf16(Ah[mt], Bl[nt], a, 0, 0, 0);
                    a = __builtin_amdgcn_mfma_f32_16x16x32_bf16(Al[mt], Bh[nt], a, 0, 0, 0);
                    a = __builtin_amdgcn_mfma_f32_16x16x32_bf16(Al[mt], Bl[nt], a, 0, 0, 0);
                    acc[mt][nt] = a;
                }
        }
        // wave-private epilogue: two 32-column halves, stage + scan, no barriers
#pragma unroll
        for (int h = 0; h < 2; ++h) {
            // store: columns 32h..32h+31 of this wave's quadrant
#pragma unroll
            for (int nt2 = 0; nt2 < 2; ++nt2) {
                const int nt = 2 * h + nt2;
                const float sqc = sq[j0 + 64 * wc + 16 * nt + lm];
                const int p = (16 * nt2 + lm + 4 * q) & 31;   // store rotation
#pragma unroll
                for (int mt = 0; mt < 4; ++mt)
#pragma unroll
                    for (int r = 0; r < 4; ++r) {
                        float d2 = sqr[mt][r] + sqc - 2.0f * acc[mt][nt][r];
                        buf[(16 * mt + 4 * q + r) * 33 + p] = fmaxf(d2, 0.0f);
                    }
            }
            // scan: lane l owns row l of the quadrant (intra-wave lgkmcnt orders LDS)
            const int colbase = j0 + 64 * wc + 32 * h;
            const float* rowp = &buf[l * 33];
            for (int s = 0; s < 32; ++s) {
                float v = rowp[s];
                int cl = (s - 4 * qrow) & 31;     // invert store rotation
                int j  = colbase + cl;
                if (v < thr_v || (v == thr_v && j < thr_i)) {
                    topk_insert(v, j, bval, bidx);
                    thr_v = bval[KNB-1]; thr_i = bidx[KNB-1];
                }
            }
        }
    }
    // cross-half merge: wave (wr,1) dumps its lists; wave (wr,0) merges + writes.
    __syncthreads();                             // all waves done with their bufs
    float* dumpV = &smem[0][0];                  // 128 rows x 10
    int*   dumpI = reinterpret_cast<int*>(&smem[0][1280]);
    if (wc == 1) {
#pragma unroll
        for (int s = 0; s < KNB; ++s) {
            dumpV[(wr * 64 + l) * KNB + s] = bval[s];
            dumpI[(wr * 64 + l) * KNB + s] = bidx[s];
        }
    }
    __syncthreads();
    if (wc == 0) {
#pragma unroll
        for (int s = 0; s < KNB; ++s)
            topk_insert(dumpV[(wr * 64 + l) * KNB + s], dumpI[(wr * 64 + l) * KNB + s],
                        bval, bidx);
        int row = i0 + 64 * wr + l;
        size_t base = (size_t)row * cstride + split * KNB;
#pragma unroll
        for (int s = 0; s < KNB; ++s) {
            cval[base + s] = bval[s];
            cidx[base + s] = bidx[s];
        }
    }
}

// ---------- 4) merge partial top-10s -> global top-10, build symmetric adjacency bitset ----------
__global__ __launch_bounds__(256) void merge_adj_kernel(
    const float* __restrict__ cval, const int* __restrict__ cidx,
    unsigned int* __restrict__ bits, int ncand, int cstride)
{
    int i = blockIdx.x * blockDim.x + threadIdx.x;
    if (i >= NN) return;
    float bval[KNB]; int bidx[KNB];
#pragma unroll
    for (int s = 0; s < KNB; ++s) { bval[s] = 3.0e38f; bidx[s] = 0x7fffffff; }
    for (int s = 0; s < ncand; ++s) {
        float v = cval[(size_t)i * cstride + s];
        int   j = cidx[(size_t)i * cstride + s];
        topk_insert(v, j, bval, bidx);
    }
#pragma unroll
    for (int s = 0; s < KNB; ++s) {
        int j = bidx[s];
        atomicOr(&bits[(size_t)i * 256 + (j >> 5)], 1u << (j & 31));
        atomicOr(&bits[(size_t)j * 256 + (i >> 5)], 1u << (i & 31));
    }
}

// ---------- 5) label init ----------
__global__ __launch_bounds__(256) void labels_init_kernel(const int* __restrict__ slab, float* __restrict__ la)
{
    int tid = blockIdx.x * blockDim.x + threadIdx.x;   // NN*64 threads
    int i = tid >> 6, c = tid & 63;
    float v = 0.f;
    if (i < NS) v = (slab[i] == c) ? 1.f : 0.f;
    la[tid] = v;
}

// ---------- 6) one propagation step: lout[i] = (1/deg_i) * sum_{j in N(i)} lin[j] ----------
__global__ __launch_bounds__(256) void prop_kernel(
    const unsigned int* __restrict__ bits, const float* __restrict__ lin, float* __restrict__ lout)
{
    int i = blockIdx.x * 4 + (threadIdx.x >> 6);
    int c = threadIdx.x & 63;
    const unsigned int* row = bits + (size_t)i * 256;
    int deg = 0;
    for (int w = 0; w < 256; ++w) deg += __popc(row[w]);
    float tinv = 1.0f / (float)deg;                    // deg >= 1 (self-loop always present)
    float acc = 0.f;
    for (int w = 0; w < 256; ++w) {
        unsigned int m = row[w];
        while (m) {
            int b = __ffs(m) - 1;
            m &= m - 1;
            int j = w * 32 + b;
            acc += __fmul_rn(tinv, lin[(size_t)j * 64 + c]);
        }
    }
    lout[(size_t)i * 64 + c] = acc;
}

// ---------- 7) argmax (first-index tie-break) -> one-hot ----------
__global__ __launch_bounds__(256) void argmax_kernel(const float* __restrict__ labels, float* __restrict__ out)
{
    int q = blockIdx.x * 4 + (threadIdx.x >> 6);   // 0..NQ-1
    int c = threadIdx.x & 63;
    float bv = labels[(size_t)(NS + q) * 64 + c];
    int   bi = c;
#pragma unroll
    for (int off = 32; off >= 1; off >>= 1) {
        float ov = __shfl_xor(bv, off, 64);
        int   oi = __shfl_xor(bi, off, 64);
        if (ov > bv || (ov == bv && oi < bi)) { bv = ov; bi = oi; }
    }
    out[(size_t)q * 64 + c] = (c == bi) ? 1.0f : 0.0f;
}

// ---------- launch ----------
extern "C" void kernel_launch(void* const* d_in, const int* in_sizes, int n_in,
                              void* d_out, int out_size, void* d_ws, size_t ws_size,
                              hipStream_t stream)
{
    const float* support = (const float*)d_in[0];
    const float* query   = (const float*)d_in[1];
    const int*   slab    = (const int*)d_in[2];
    const float* W       = (const float*)d_in[3];
    float* out = (float*)d_out;
    char*  ws  = (char*)d_ws;

    // workspace (phase-aliased):
    //   [0, 4M)      Ghi (bf16 hi, fragment-packed)   -> bits [0,8M) after dist
    //   [4M, 8M)     Glo (bf16 lo)
    //   [8M, +64K)   sqpart
    //   [+32K)       sq
    //   cval / cidx  (nsplit-dependent)               -> la / lb after merge
    const size_t GHI_OFF = 0;
    const size_t GLO_OFF = 4194304;
    const size_t SQP_OFF = 8388608;
    const size_t SQ_OFF  = 8454144;
    const size_t CV_OFF  = 8486912;

    // nsplit=16 -> grid 64x16=1024 = 4 blocks/CU (matches 33792 B LDS residency);
    // needs 2 x 8192*160*4 B candidate arrays. Fallback 8 if workspace is tight.
    int nsplit = 8;
    if (ws_size >= CV_OFF + 2ull * (size_t)NN * 16 * KNB * 4) nsplit = 16;
    const int cstride = nsplit * KNB;
    const size_t candBytes = (size_t)NN * cstride * 4;
    const size_t CI_OFF = CV_OFF + candBytes;

    bf16x8*       Ghi  = (bf16x8*)(ws + GHI_OFF);
    bf16x8*       Glo  = (bf16x8*)(ws + GLO_OFF);
    unsigned int* bits = (unsigned int*)(ws + GHI_OFF);       // aliases Ghi/Glo (dead after dist)
    float*        sqp  = (float*)(ws + SQP_OFF);
    float*        sq   = (float*)(ws + SQ_OFF);
    float*        cval = (float*)(ws + CV_OFF);
    int*          cidx = (int*)  (ws + CI_OFF);
    float*        la   = (float*)(ws + CV_OFF);               // aliases cval (dead after merge)
    float*        lb   = (float*)(ws + CI_OFF);               // aliases cidx

    embed_kernel<<<dim3(128, 2), 256, 0, stream>>>(support, query, W, Ghi, Glo, sqp);
    sqsum_kernel<<<NN / 256, 256, 0, stream>>>(sqp, sq);
    dist_topk_kernel<<<dim3(64, nsplit), 256, 0, stream>>>(Ghi, Glo, sq, cval, cidx,
                                                           nsplit, cstride);
    hipMemsetAsync(bits, 0, (size_t)NN * 256 * sizeof(unsigned int), stream);   // Ghi/Glo dead now
    merge_adj_kernel<<<NN / 256, 256, 0, stream>>>(cval, cidx, bits, cstride, cstride);
    labels_init_kernel<<<(NN * 64) / 256, 256, 0, stream>>>(slab, la);          // cval dead now
    prop_kernel<<<NN / 4, 256, 0, stream>>>(bits, la, lb);
    prop_kernel<<<NN / 4, 256, 0, stream>>>(bits, lb, la);
    prop_kernel<<<NN / 4, 256, 0, stream>>>(bits, la, lb);
    argmax_kernel<<<NQ / 4, 256, 0, stream>>>(lb, out);
}

// Round 7
// 809.204 us; speedup vs baseline: 1.4463x; 1.4463x over previous
//
#include <hip/hip_runtime.h>
#include <stdint.h>

#define NS   2048
#define NQ   6144
#define NN   8192      // total nodes
#define IND  512
#define DM   256
#define KNB  10
#define PCAP 1536      // prop edge-list capacity per node

typedef short bf16x8 __attribute__((ext_vector_type(8)));
typedef float f32x4  __attribute__((ext_vector_type(4)));

// exact RNE fp32 -> bf16 (bits); bf16 exp range == fp32, no denormal hazard
__device__ __forceinline__ unsigned short f2bf(float v)
{
    unsigned int u = __float_as_uint(v);
    unsigned int r = (u + 0x7fffu + ((u >> 16) & 1u)) >> 16;
    return (unsigned short)r;
}
__device__ __forceinline__ float bf2f(unsigned short h)
{
    return __uint_as_float(((unsigned int)h) << 16);
}

// lexicographic (value, index) insert into sorted-ascending top-10 registers
__device__ __forceinline__ void topk_insert(float v, int j, float bval[KNB], int bidx[KNB])
{
    bool better = (v < bval[KNB-1]) || (v == bval[KNB-1] && j < bidx[KNB-1]);
    if (better) {
        float cv = v; int ci = j;
#pragma unroll
        for (int q = 0; q < KNB; ++q) {
            bool sw = (cv < bval[q]) || (cv == bval[q] && ci < bidx[q]);
            if (sw) {
                float tv = bval[q]; bval[q] = cv; cv = tv;
                int   ti = bidx[q]; bidx[q] = ci; ci = ti;
            }
        }
    }
}

// ---------- 1) embed: E = concat(support,query) @ W (8192x512x256), 64x64 tiles.
// grid 128x4 = 512 blocks = 2/CU (was 1/CU at 64x128 -> latency-exposed).
// Per-output fp32 FMA order identical to prior rounds (k ascending).
// Epilogue packs E into MFMA-fragment-ordered bf16 hi/lo arrays
//   G[c][node][q][j]  (c=k/32, q=(k>>3)&3, j=k&7; 16 B per (node,q))
// and writes per-row partial squared norms (exact fp32 from acc).
__global__ __launch_bounds__(256) void embed_kernel(
    const float* __restrict__ support, const float* __restrict__ query,
    const float* __restrict__ W, bf16x8* __restrict__ Ghi, bf16x8* __restrict__ Glo,
    float* __restrict__ sqpart)
{
    __shared__ float smem[64 * 68];      // K-loop: A^T 32x68 | B 32x68 ; epilogue: Etile 64x68
    __shared__ float sqred[64 * 17];
    float* smemA = smem;
    float* smemB = smem + 32 * 68;
    const int t  = threadIdx.x;
    const int i0 = blockIdx.x * 64;
    const int n0 = blockIdx.y * 64;
    const int tx = t & 15, ty = t >> 4;

    float acc[4][4];
#pragma unroll
    for (int m = 0; m < 4; ++m)
#pragma unroll
        for (int n = 0; n < 4; ++n) acc[m][n] = 0.f;

    for (int kc = 0; kc < IND; kc += 32) {
        {   // A: rows i0..i0+64 of concat(support,query), cols kc..kc+32, transposed
            int a  = t >> 2;            // 0..63
            int cg = (t & 3) * 8;       // 0,8,16,24
            int g  = i0 + a;
            const float* src = (g < NS) ? (support + (size_t)g * IND)
                                        : (query + (size_t)(g - NS) * IND);
            src += kc + cg;
#pragma unroll
            for (int q = 0; q < 2; ++q) {
                float4 v = *reinterpret_cast<const float4*>(src + q * 4);
                smemA[(cg + q*4 + 0) * 68 + a] = v.x;
                smemA[(cg + q*4 + 1) * 68 + a] = v.y;
                smemA[(cg + q*4 + 2) * 68 + a] = v.z;
                smemA[(cg + q*4 + 3) * 68 + a] = v.w;
            }
        }
        {   // B: W rows kc..kc+32, cols n0..n0+64 (k-major)
            int r  = t >> 3;            // 0..31
            int cg = (t & 7) * 8;       // 0..56
            const float* src = W + (size_t)(kc + r) * DM + n0 + cg;
#pragma unroll
            for (int q = 0; q < 2; ++q) {
                float4 v = *reinterpret_cast<const float4*>(src + q * 4);
                *reinterpret_cast<float4*>(&smemB[r * 68 + cg + q * 4]) = v;
            }
        }
        __syncthreads();
#pragma unroll
        for (int kk = 0; kk < 32; ++kk) {
            float4 a0 = *reinterpret_cast<const float4*>(&smemA[kk * 68 + ty * 4]);
            float4 b0 = *reinterpret_cast<const float4*>(&smemB[kk * 68 + tx * 4]);
            float af[4] = {a0.x, a0.y, a0.z, a0.w};
            float bf[4] = {b0.x, b0.y, b0.z, b0.w};
#pragma unroll
            for (int m = 0; m < 4; ++m)
#pragma unroll
                for (int n = 0; n < 4; ++n)
                    acc[m][n] += af[m] * bf[n];
        }
        __syncthreads();
    }
    // epilogue: partial row norms + stage E tile to LDS (smemA/B dead), pack bf16 hi/lo
#pragma unroll
    for (int m = 0; m < 4; ++m) {
        float s = 0.f;
#pragma unroll
        for (int n = 0; n < 4; ++n) {
            float v = acc[m][n];
            s += v * v;
            smem[(ty * 4 + m) * 68 + tx * 4 + n] = v;
        }
        sqred[(ty * 4 + m) * 17 + tx] = s;
    }
    __syncthreads();
#pragma unroll
    for (int e = 0; e < 2; ++e) {
        int g  = t * 2 + e;              // 0..511 = 64 rows x 2 chunks x 4 quads
        int rl = g >> 3;
        int ch = (g >> 2) & 1;
        int qq = g & 3;
        const float* ep = &smem[rl * 68 + ch * 32 + qq * 8];
        bf16x8 h8, l8;
#pragma unroll
        for (int jj = 0; jj < 8; ++jj) {
            float v = ep[jj];
            unsigned short hu = f2bf(v);
            float hf = bf2f(hu);
            unsigned short lu = f2bf(v - hf);
            h8[jj] = (short)hu;
            l8[jj] = (short)lu;
        }
        int cc = blockIdx.y * 2 + ch;
        size_t gi = ((size_t)cc * NN + i0 + rl) * 4 + qq;
        Ghi[gi] = h8;
        Glo[gi] = l8;
    }
    if (t < 64) {
        float s = 0.f;
#pragma unroll
        for (int x = 0; x < 16; ++x) s += sqred[t * 17 + x];
        sqpart[(size_t)blockIdx.y * NN + i0 + t] = s;
    }
}

// ---------- 2) combine the four column-quarter partial norms ----------
__global__ __launch_bounds__(256) void sqsum_kernel(const float* __restrict__ sqpart,
                                                    float* __restrict__ sq)
{
    int i = blockIdx.x * 256 + threadIdx.x;
    sq[i] = ((sqpart[i] + sqpart[NN + i]) + sqpart[2 * NN + i]) + sqpart[3 * NN + i];
}

// ---------- 3) fused distance MFMA-GEMM + streaming per-row top-10 ----------
// bf16 2-way split (hi+lo), 4 MFMA products into fp32 acc (exact product of the
// bf16-split representation; validated r5/r6, absmax 0). Block 128x128, 4 waves
// 2x2, wave tile 64x64. Wave-private barrier-free epilogue (64x33 LDS patch,
// store rotation + 2-way-bank scan). Scan reads batched x4 (independent ds_reads
// -> 4x MLP) with an exact min-guard (skip only when min4 > thr strictly).
__global__ __launch_bounds__(256) void dist_topk_kernel(
    const bf16x8* __restrict__ Ghi, const bf16x8* __restrict__ Glo,
    const float* __restrict__ sq, float* __restrict__ cval, int* __restrict__ cidx,
    int nsplit, int cstride)
{
    __shared__ float smem[4][64 * 33];           // 33792 B, per-wave private
    const int t  = threadIdx.x;
    const int l  = t & 63, w = t >> 6;
    const int wr = w >> 1, wc = w & 1;
    const int lm = l & 15, q = l >> 4;
    const int i0 = blockIdx.x * 128;
    const int split = blockIdx.y;
    float* buf = smem[w];

    f32x4 sqr[4];
#pragma unroll
    for (int mt = 0; mt < 4; ++mt)
        sqr[mt] = *reinterpret_cast<const f32x4*>(&sq[i0 + 64 * wr + 16 * mt + 4 * q]);

    const size_t aBase = (size_t)(i0 + 64 * wr + lm) * 4 + q;   // bf16x8 units
    const int    cb    = 64 * wc + lm;
    const int    qrow  = (l >> 2) & 3;           // (row%16)>>2 for scan row = l

    float bval[KNB]; int bidx[KNB];
#pragma unroll
    for (int s = 0; s < KNB; ++s) { bval[s] = 3.0e38f; bidx[s] = 0x7fffffff; }
    float thr_v = 3.0e38f; int thr_i = 0x7fffffff;

    const int jtb = (split * 64) / nsplit;
    const int jte = ((split + 1) * 64) / nsplit;
    for (int jt = jtb; jt < jte; ++jt) {
        const int j0 = jt * 128;
        const size_t bBase = (size_t)(j0 + cb) * 4 + q;

        f32x4 acc[4][4];
#pragma unroll
        for (int mt = 0; mt < 4; ++mt)
#pragma unroll
            for (int nt = 0; nt < 4; ++nt) acc[mt][nt] = (f32x4){0.f, 0.f, 0.f, 0.f};

        for (int c = 0; c < 8; ++c) {
            const size_t co = (size_t)c * (NN * 4);
            bf16x8 Ah[4], Al[4], Bh[4], Bl[4];
#pragma unroll
            for (int mt = 0; mt < 4; ++mt) {
                Ah[mt] = Ghi[aBase + co + mt * 64];
                Al[mt] = Glo[aBase + co + mt * 64];
            }
#pragma unroll
            for (int nt = 0; nt < 4; ++nt) {
                Bh[nt] = Ghi[bBase + co + nt * 64];
                Bl[nt] = Glo[bBase + co + nt * 64];
            }
#pragma unroll
            for (int mt = 0; mt < 4; ++mt)
#pragma unroll
                for (int nt = 0; nt < 4; ++nt) {
                    f32x4 a = acc[mt][nt];
                    a = __builtin_amdgcn_mfma_f32_16x16x32_bf16(Ah[mt], Bh[nt], a, 0, 0, 0);
                    a = __builtin_amdgcn_mfma_f32_16x16x32_bf16(Ah[mt], Bl[nt], a, 0, 0, 0);
                    a = __builtin_amdgcn_mfma_f32_16x16x32_bf16(Al[mt], Bh[nt], a, 0, 0, 0);
                    a = __builtin_amdgcn_mfma_f32_16x16x32_bf16(Al[mt], Bl[nt], a, 0, 0, 0);
                    acc[mt][nt] = a;
                }
        }
        // wave-private epilogue: two 32-column halves, stage + scan, no barriers
#pragma unroll
        for (int h = 0; h < 2; ++h) {
#pragma unroll
            for (int nt2 = 0; nt2 < 2; ++nt2) {
                const int nt = 2 * h + nt2;
                const float sqc = sq[j0 + 64 * wc + 16 * nt + lm];
                const int p = (16 * nt2 + lm + 4 * q) & 31;   // store rotation
#pragma unroll
                for (int mt = 0; mt < 4; ++mt)
#pragma unroll
                    for (int r = 0; r < 4; ++r) {
                        float d2 = sqr[mt][r] + sqc - 2.0f * acc[mt][nt][r];
                        buf[(16 * mt + 4 * q + r) * 33 + p] = fmaxf(d2, 0.0f);
                    }
            }
            const int colbase = j0 + 64 * wc + 32 * h;
            const float* rowp = &buf[l * 33];
            for (int s = 0; s < 32; s += 4) {
                float v0 = rowp[s], v1 = rowp[s + 1], v2 = rowp[s + 2], v3 = rowp[s + 3];
                float mn = fminf(fminf(v0, v1), fminf(v2, v3));
                if (mn <= thr_v) {                // exact: skip only if strictly worse
                    float vv[4] = {v0, v1, v2, v3};
#pragma unroll
                    for (int e = 0; e < 4; ++e) {
                        float v = vv[e];
                        int cl = (s + e - 4 * qrow) & 31;   // invert store rotation
                        int j  = colbase + cl;
                        if (v < thr_v || (v == thr_v && j < thr_i)) {
                            topk_insert(v, j, bval, bidx);
                            thr_v = bval[KNB-1]; thr_i = bidx[KNB-1];
                        }
                    }
                }
            }
        }
    }
    // cross-half merge: wave (wr,1) dumps its lists; wave (wr,0) merges + writes.
    __syncthreads();
    float* dumpV = &smem[0][0];
    int*   dumpI = reinterpret_cast<int*>(&smem[0][1280]);
    if (wc == 1) {
#pragma unroll
        for (int s = 0; s < KNB; ++s) {
            dumpV[(wr * 64 + l) * KNB + s] = bval[s];
            dumpI[(wr * 64 + l) * KNB + s] = bidx[s];
        }
    }
    __syncthreads();
    if (wc == 0) {
#pragma unroll
        for (int s = 0; s < KNB; ++s)
            topk_insert(dumpV[(wr * 64 + l) * KNB + s], dumpI[(wr * 64 + l) * KNB + s],
                        bval, bidx);
        int row = i0 + 64 * wr + l;
        size_t base = (size_t)row * cstride + split * KNB;
#pragma unroll
        for (int s = 0; s < KNB; ++s) {
            cval[base + s] = bval[s];
            cidx[base + s] = bidx[s];
        }
    }
}

// ---------- 4) merge partial top-10s -> global top-10, build symmetric adjacency bitset ----------
__global__ __launch_bounds__(256) void merge_adj_kernel(
    const float* __restrict__ cval, const int* __restrict__ cidx,
    unsigned int* __restrict__ bits, int ncand, int cstride)
{
    int i = blockIdx.x * blockDim.x + threadIdx.x;
    if (i >= NN) return;
    float bval[KNB]; int bidx[KNB];
#pragma unroll
    for (int s = 0; s < KNB; ++s) { bval[s] = 3.0e38f; bidx[s] = 0x7fffffff; }
    for (int s = 0; s < ncand; ++s) {
        float v = cval[(size_t)i * cstride + s];
        int   j = cidx[(size_t)i * cstride + s];
        topk_insert(v, j, bval, bidx);
    }
#pragma unroll
    for (int s = 0; s < KNB; ++s) {
        int j = bidx[s];
        atomicOr(&bits[(size_t)i * 256 + (j >> 5)], 1u << (j & 31));
        atomicOr(&bits[(size_t)j * 256 + (i >> 5)], 1u << (i & 31));
    }
}

// ---------- 5) label init ----------
__global__ __launch_bounds__(256) void labels_init_kernel(const int* __restrict__ slab, float* __restrict__ la)
{
    int tid = blockIdx.x * blockDim.x + threadIdx.x;   // NN*64 threads
    int i = tid >> 6, c = tid & 63;
    float v = 0.f;
    if (i < NS) v = (slab[i] == c) ? 1.f : 0.f;
    la[tid] = v;
}

// ---------- 6) one propagation step: lout[i] = sum_j (1/deg_i)*lin[j] over N(i), j ascending.
// Two-phase: lanes extract set bits into an ORDERED LDS edge list (shuffle prefix
// scan keeps j ascending -> identical fp32 sum order to the bitset walk), then a
// countable gather loop unrolled x4 (batched independent loads). Fallback to the
// direct bitset walk if deg > PCAP (cannot trigger at k=10 on this data, but safe).
__global__ __launch_bounds__(256) void prop_kernel(
    const unsigned int* __restrict__ bits, const float* __restrict__ lin, float* __restrict__ lout)
{
    __shared__ int lists[4][PCAP];
    const int grp = threadIdx.x >> 6;
    const int c   = threadIdx.x & 63;
    const int i   = blockIdx.x * 4 + grp;
    const unsigned int* row = bits + (size_t)i * 256;

    unsigned int mw[4];
#pragma unroll
    for (int k = 0; k < 4; ++k) mw[k] = row[4 * c + k];
    int cnt = __popc(mw[0]) + __popc(mw[1]) + __popc(mw[2]) + __popc(mw[3]);
    int incl = cnt;
#pragma unroll
    for (int d = 1; d < 64; d <<= 1) {
        int nb = __shfl_up(incl, d, 64);
        if (c >= d) incl += nb;
    }
    const int off = incl - cnt;
    const int deg = __shfl(incl, 63, 64);
    const bool use_list = (deg <= PCAP);

    if (use_list) {
        int p = off;
#pragma unroll
        for (int k = 0; k < 4; ++k) {
            unsigned int m = mw[k];
            while (m) {
                int b = __ffs(m) - 1;
                m &= m - 1;
                lists[grp][p++] = (4 * c + k) * 32 + b;
            }
        }
    }
    __syncthreads();

    const float tinv = 1.0f / (float)deg;          // deg >= 1 (self-loop)
    float acc = 0.f;
    if (use_list) {
        const int* lst = lists[grp];
        int d = 0;
        for (; d + 4 <= deg; d += 4) {
            int j0 = lst[d], j1 = lst[d + 1], j2 = lst[d + 2], j3 = lst[d + 3];
            float x0 = lin[(size_t)j0 * 64 + c];
            float x1 = lin[(size_t)j1 * 64 + c];
            float x2 = lin[(size_t)j2 * 64 + c];
            float x3 = lin[(size_t)j3 * 64 + c];
            acc += __fmul_rn(tinv, x0);
            acc += __fmul_rn(tinv, x1);
            acc += __fmul_rn(tinv, x2);
            acc += __fmul_rn(tinv, x3);
        }
        for (; d < deg; ++d) {
            int j = lst[d];
            acc += __fmul_rn(tinv, lin[(size_t)j * 64 + c]);
        }
    } else {
        for (int w2 = 0; w2 < 256; ++w2) {
            unsigned int m = row[w2];
            while (m) {
                int b = __ffs(m) - 1;
                m &= m - 1;
                int j = w2 * 32 + b;
                acc += __fmul_rn(tinv, lin[(size_t)j * 64 + c]);
            }
        }
    }
    lout[(size_t)i * 64 + c] = acc;
}

// ---------- 7) argmax (first-index tie-break) -> one-hot ----------
__global__ __launch_bounds__(256) void argmax_kernel(const float* __restrict__ labels, float* __restrict__ out)
{
    int q = blockIdx.x * 4 + (threadIdx.x >> 6);   // 0..NQ-1
    int c = threadIdx.x & 63;
    float bv = labels[(size_t)(NS + q) * 64 + c];
    int   bi = c;
#pragma unroll
    for (int off = 32; off >= 1; off >>= 1) {
        float ov = __shfl_xor(bv, off, 64);
        int   oi = __shfl_xor(bi, off, 64);
        if (ov > bv || (ov == bv && oi < bi)) { bv = ov; bi = oi; }
    }
    out[(size_t)q * 64 + c] = (c == bi) ? 1.0f : 0.0f;
}

// ---------- launch ----------
extern "C" void kernel_launch(void* const* d_in, const int* in_sizes, int n_in,
                              void* d_out, int out_size, void* d_ws, size_t ws_size,
                              hipStream_t stream)
{
    const float* support = (const float*)d_in[0];
    const float* query   = (const float*)d_in[1];
    const int*   slab    = (const int*)d_in[2];
    const float* W       = (const float*)d_in[3];
    float* out = (float*)d_out;
    char*  ws  = (char*)d_ws;

    // workspace (phase-aliased):
    //   [0, 4M)      Ghi  -> bits [0,8M) after dist
    //   [4M, 8M)     Glo
    //   [8M, +32K)   sq (live through dist)
    //   [CV_OFF ...) sqpart (embed->sqsum only) / cval (dist->merge) / la
    //   [CI_OFF ...) cidx (dist->merge) / lb
    const size_t GHI_OFF = 0;
    const size_t GLO_OFF = 4194304;
    const size_t SQ_OFF  = 8388608;
    const size_t CV_OFF  = 8421376;

    // adaptive split count vs ws_size: 16 -> 4 blk/CU, 12 -> 3 blk/CU, else 8.
    // (r6 learned: ws in [13.73, 18.97) MB, so expect 12 on a 16 MB workspace.)
    int nsplit = 8;
    if      (ws_size >= CV_OFF + 2ull * NN * 16 * KNB * 4) nsplit = 16;
    else if (ws_size >= CV_OFF + 2ull * NN * 12 * KNB * 4) nsplit = 12;
    const int cstride = nsplit * KNB;
    const size_t candBytes = (size_t)NN * cstride * 4;
    const size_t CI_OFF = CV_OFF + candBytes;

    bf16x8*       Ghi  = (bf16x8*)(ws + GHI_OFF);
    bf16x8*       Glo  = (bf16x8*)(ws + GLO_OFF);
    unsigned int* bits = (unsigned int*)(ws + GHI_OFF);   // aliases Ghi/Glo (dead after dist)
    float*        sq   = (float*)(ws + SQ_OFF);
    float*        sqp  = (float*)(ws + CV_OFF);           // aliases cval (dead before dist writes)
    float*        cval = (float*)(ws + CV_OFF);
    int*          cidx = (int*)  (ws + CI_OFF);
    float*        la   = (float*)(ws + CV_OFF);           // aliases cval (dead after merge)
    float*        lb   = (float*)(ws + CI_OFF);           // aliases cidx

    embed_kernel<<<dim3(128, 4), 256, 0, stream>>>(support, query, W, Ghi, Glo, sqp);
    sqsum_kernel<<<NN / 256, 256, 0, stream>>>(sqp, sq);
    dist_topk_kernel<<<dim3(64, nsplit), 256, 0, stream>>>(Ghi, Glo, sq, cval, cidx,
                                                           nsplit, cstride);
    hipMemsetAsync(bits, 0, (size_t)NN * 256 * sizeof(unsigned int), stream);   // Ghi/Glo dead
    merge_adj_kernel<<<NN / 256, 256, 0, stream>>>(cval, cidx, bits, cstride, cstride);
    labels_init_kernel<<<(NN * 64) / 256, 256, 0, stream>>>(slab, la);          // cval dead
    prop_kernel<<<NN / 4, 256, 0, stream>>>(bits, la, lb);
    prop_kernel<<<NN / 4, 256, 0, stream>>>(bits, lb, la);
    prop_kernel<<<NN / 4, 256, 0, stream>>>(bits, la, lb);
    argmax_kernel<<<NQ / 4, 256, 0, stream>>>(lb, out);
}

// Round 8
// 769.680 us; speedup vs baseline: 1.5206x; 1.0514x over previous
//
#include <hip/hip_runtime.h>
#include <stdint.h>

#define NS   2048
#define NQ   6144
#define NN   8192      // total nodes
#define IND  512
#define DM   256
#define KNB  10
#define NSPLIT 8
#define PCAP 1536      // prop edge-list capacity per node

typedef short bf16x8 __attribute__((ext_vector_type(8)));
typedef float f32x4  __attribute__((ext_vector_type(4)));

// exact RNE fp32 -> bf16 (bits); bf16 exp range == fp32, no denormal hazard
__device__ __forceinline__ unsigned short f2bf(float v)
{
    unsigned int u = __float_as_uint(v);
    unsigned int r = (u + 0x7fffu + ((u >> 16) & 1u)) >> 16;
    return (unsigned short)r;
}
__device__ __forceinline__ float bf2f(unsigned short h)
{
    return __uint_as_float(((unsigned int)h) << 16);
}

// lexicographic (value, index) insert into sorted-ascending top-10 registers
__device__ __forceinline__ void topk_insert(float v, int j, float bval[KNB], int bidx[KNB])
{
    bool better = (v < bval[KNB-1]) || (v == bval[KNB-1] && j < bidx[KNB-1]);
    if (better) {
        float cv = v; int ci = j;
#pragma unroll
        for (int q = 0; q < KNB; ++q) {
            bool sw = (cv < bval[q]) || (cv == bval[q] && ci < bidx[q]);
            if (sw) {
                float tv = bval[q]; bval[q] = cv; cv = tv;
                int   ti = bidx[q]; bidx[q] = ci; ci = ti;
            }
        }
    }
}

// ---------- 1) embed: E = concat(support,query) @ W (8192x512x256), 64x64 tiles.
// grid 128x4 = 512 blocks = 2/CU. Per-output fp32 FMA order: k ascending.
// Epilogue packs E into MFMA-fragment-ordered bf16 hi/lo arrays
//   G[c][node][q][j]  (c=k/32, q=(k>>3)&3, j=k&7; 16 B per (node,q))
// and writes per-row partial squared norms (exact fp32 from acc).
__global__ __launch_bounds__(256) void embed_kernel(
    const float* __restrict__ support, const float* __restrict__ query,
    const float* __restrict__ W, bf16x8* __restrict__ Ghi, bf16x8* __restrict__ Glo,
    float* __restrict__ sqpart)
{
    __shared__ float smem[64 * 68];      // K-loop: A^T 32x68 | B 32x68 ; epilogue: Etile 64x68
    __shared__ float sqred[64 * 17];
    float* smemA = smem;
    float* smemB = smem + 32 * 68;
    const int t  = threadIdx.x;
    const int i0 = blockIdx.x * 64;
    const int n0 = blockIdx.y * 64;
    const int tx = t & 15, ty = t >> 4;

    float acc[4][4];
#pragma unroll
    for (int m = 0; m < 4; ++m)
#pragma unroll
        for (int n = 0; n < 4; ++n) acc[m][n] = 0.f;

    for (int kc = 0; kc < IND; kc += 32) {
        {   // A: rows i0..i0+64 of concat(support,query), cols kc..kc+32, transposed
            int a  = t >> 2;            // 0..63
            int cg = (t & 3) * 8;       // 0,8,16,24
            int g  = i0 + a;
            const float* src = (g < NS) ? (support + (size_t)g * IND)
                                        : (query + (size_t)(g - NS) * IND);
            src += kc + cg;
#pragma unroll
            for (int q = 0; q < 2; ++q) {
                float4 v = *reinterpret_cast<const float4*>(src + q * 4);
                smemA[(cg + q*4 + 0) * 68 + a] = v.x;
                smemA[(cg + q*4 + 1) * 68 + a] = v.y;
                smemA[(cg + q*4 + 2) * 68 + a] = v.z;
                smemA[(cg + q*4 + 3) * 68 + a] = v.w;
            }
        }
        {   // B: W rows kc..kc+32, cols n0..n0+64 (k-major)
            int r  = t >> 3;            // 0..31
            int cg = (t & 7) * 8;       // 0..56
            const float* src = W + (size_t)(kc + r) * DM + n0 + cg;
#pragma unroll
            for (int q = 0; q < 2; ++q) {
                float4 v = *reinterpret_cast<const float4*>(src + q * 4);
                *reinterpret_cast<float4*>(&smemB[r * 68 + cg + q * 4]) = v;
            }
        }
        __syncthreads();
#pragma unroll
        for (int kk = 0; kk < 32; ++kk) {
            float4 a0 = *reinterpret_cast<const float4*>(&smemA[kk * 68 + ty * 4]);
            float4 b0 = *reinterpret_cast<const float4*>(&smemB[kk * 68 + tx * 4]);
            float af[4] = {a0.x, a0.y, a0.z, a0.w};
            float bf[4] = {b0.x, b0.y, b0.z, b0.w};
#pragma unroll
            for (int m = 0; m < 4; ++m)
#pragma unroll
                for (int n = 0; n < 4; ++n)
                    acc[m][n] += af[m] * bf[n];
        }
        __syncthreads();
    }
    // epilogue: partial row norms + stage E tile to LDS (smemA/B dead), pack bf16 hi/lo
#pragma unroll
    for (int m = 0; m < 4; ++m) {
        float s = 0.f;
#pragma unroll
        for (int n = 0; n < 4; ++n) {
            float v = acc[m][n];
            s += v * v;
            smem[(ty * 4 + m) * 68 + tx * 4 + n] = v;
        }
        sqred[(ty * 4 + m) * 17 + tx] = s;
    }
    __syncthreads();
#pragma unroll
    for (int e = 0; e < 2; ++e) {
        int g  = t * 2 + e;              // 0..511 = 64 rows x 2 chunks x 4 quads
        int rl = g >> 3;
        int ch = (g >> 2) & 1;
        int qq = g & 3;
        const float* ep = &smem[rl * 68 + ch * 32 + qq * 8];
        bf16x8 h8, l8;
#pragma unroll
        for (int jj = 0; jj < 8; ++jj) {
            float v = ep[jj];
            unsigned short hu = f2bf(v);
            float hf = bf2f(hu);
            unsigned short lu = f2bf(v - hf);
            h8[jj] = (short)hu;
            l8[jj] = (short)lu;
        }
        int cc = blockIdx.y * 2 + ch;
        size_t gi = ((size_t)cc * NN + i0 + rl) * 4 + qq;
        Ghi[gi] = h8;
        Glo[gi] = l8;
    }
    if (t < 64) {
        float s = 0.f;
#pragma unroll
        for (int x = 0; x < 16; ++x) s += sqred[t * 17 + x];
        sqpart[(size_t)blockIdx.y * NN + i0 + t] = s;
    }
}

// ---------- 2) combine the four column-quarter partial norms ----------
__global__ __launch_bounds__(256) void sqsum_kernel(const float* __restrict__ sqpart,
                                                    float* __restrict__ sq)
{
    int i = blockIdx.x * 256 + threadIdx.x;
    sq[i] = ((sqpart[i] + sqpart[NN + i]) + sqpart[2 * NN + i]) + sqpart[3 * NN + i];
}

// ---------- 3) fused distance MFMA-GEMM + streaming per-row top-10 ----------
// bf16 2-way split (hi+lo), 4 MFMA products into fp32 acc (validated r5-r7, absmax 0).
// RESTRUCTURED for occupancy: block = 64 rows x 128 cols, 4 waves each owning a
// 64x32 column strip (4x2 MFMA tiles). Grid 128x8 = 1024 blocks = 4/CU; VGPR
// ~110-125 -> 4 waves/SIMD -> 16 waves/CU (2x r7's wave supply) with the same
// candidate-array footprint (8192 rows x 80). Wave-private barrier-free epilogue:
// 64x33 LDS patch (store rotation p=(cs+4q)&31 -> exact 2-way banks; scan
// (l+s)%32 -> 2-way). Scan batched x4 with exact min-guard. End: 4-wave merge
// per row via LDS (2 barriers total).
__global__ __launch_bounds__(256) void dist_topk_kernel(
    const bf16x8* __restrict__ Ghi, const bf16x8* __restrict__ Glo,
    const float* __restrict__ sq, float* __restrict__ cval, int* __restrict__ cidx)
{
    __shared__ float smem[4][64 * 33];           // 33792 B, per-wave private
    const int t  = threadIdx.x;
    const int l  = t & 63, w = t >> 6;
    const int lm = l & 15, q = l >> 4;
    const int i0 = blockIdx.x * 64;
    const int split = blockIdx.y;
    float* buf = smem[w];

    const size_t aBase = (size_t)(i0 + lm) * 4 + q;   // bf16x8 units
    const int    qrow  = (l >> 2) & 3;                // (row%16)>>2 for scan row = l

    float bval[KNB]; int bidx[KNB];
#pragma unroll
    for (int s = 0; s < KNB; ++s) { bval[s] = 3.0e38f; bidx[s] = 0x7fffffff; }
    float thr_v = 3.0e38f; int thr_i = 0x7fffffff;

    for (int jt = split * 8; jt < split * 8 + 8; ++jt) {
        const int j0 = jt * 128;
        const int c0 = j0 + 32 * w;                   // this wave's column strip
        const size_t bBase = (size_t)(c0 + lm) * 4 + q;

        f32x4 acc[4][2];
#pragma unroll
        for (int mt = 0; mt < 4; ++mt)
#pragma unroll
            for (int nt = 0; nt < 2; ++nt) acc[mt][nt] = (f32x4){0.f, 0.f, 0.f, 0.f};

        for (int c = 0; c < 8; ++c) {
            const size_t co = (size_t)c * (NN * 4);
            bf16x8 Ah[4], Al[4], Bh[2], Bl[2];
#pragma unroll
            for (int mt = 0; mt < 4; ++mt) {
                Ah[mt] = Ghi[aBase + co + mt * 64];
                Al[mt] = Glo[aBase + co + mt * 64];
            }
#pragma unroll
            for (int nt = 0; nt < 2; ++nt) {
                Bh[nt] = Ghi[bBase + co + nt * 64];
                Bl[nt] = Glo[bBase + co + nt * 64];
            }
#pragma unroll
            for (int mt = 0; mt < 4; ++mt)
#pragma unroll
                for (int nt = 0; nt < 2; ++nt) {
                    f32x4 a = acc[mt][nt];
                    a = __builtin_amdgcn_mfma_f32_16x16x32_bf16(Ah[mt], Bh[nt], a, 0, 0, 0);
                    a = __builtin_amdgcn_mfma_f32_16x16x32_bf16(Ah[mt], Bl[nt], a, 0, 0, 0);
                    a = __builtin_amdgcn_mfma_f32_16x16x32_bf16(Al[mt], Bh[nt], a, 0, 0, 0);
                    a = __builtin_amdgcn_mfma_f32_16x16x32_bf16(Al[mt], Bl[nt], a, 0, 0, 0);
                    acc[mt][nt] = a;
                }
        }
        // wave-private epilogue: stage the 64x32 strip, then scan — no barriers
#pragma unroll
        for (int nt = 0; nt < 2; ++nt) {
            const float sqc = sq[c0 + 16 * nt + lm];
            const int p = (16 * nt + lm + 4 * q) & 31;    // store rotation
#pragma unroll
            for (int mt = 0; mt < 4; ++mt) {
                const f32x4 sqr = *reinterpret_cast<const f32x4*>(&sq[i0 + 16 * mt + 4 * q]);
#pragma unroll
                for (int r = 0; r < 4; ++r) {
                    float d2 = sqr[r] + sqc - 2.0f * acc[mt][nt][r];
                    buf[(16 * mt + 4 * q + r) * 33 + p] = fmaxf(d2, 0.0f);
                }
            }
        }
        // scan: lane l owns row l (intra-wave lgkmcnt orders LDS RAW)
        const float* rowp = &buf[l * 33];
        for (int s = 0; s < 32; s += 4) {
            float v0 = rowp[s], v1 = rowp[s + 1], v2 = rowp[s + 2], v3 = rowp[s + 3];
            float mn = fminf(fminf(v0, v1), fminf(v2, v3));
            if (mn <= thr_v) {                // exact: skip only if strictly worse
                float vv[4] = {v0, v1, v2, v3};
#pragma unroll
                for (int e = 0; e < 4; ++e) {
                    float v = vv[e];
                    int cs = (s + e - 4 * qrow) & 31;     // invert store rotation
                    int j  = c0 + cs;
                    if (v < thr_v || (v == thr_v && j < thr_i)) {
                        topk_insert(v, j, bval, bidx);
                        thr_v = bval[KNB-1]; thr_i = bidx[KNB-1];
                    }
                }
            }
        }
    }
    // 4-wave merge per row: waves 1..3 dump their lists; wave 0 merges + writes.
    __syncthreads();
    float* dumpV = &smem[0][0];                       // 3*64*10 floats = 7680 B
    int*   dumpI = reinterpret_cast<int*>(&smem[1][0]);
    if (w != 0) {
#pragma unroll
        for (int s = 0; s < KNB; ++s) {
            dumpV[((w - 1) * 64 + l) * KNB + s] = bval[s];
            dumpI[((w - 1) * 64 + l) * KNB + s] = bidx[s];
        }
    }
    __syncthreads();
    if (w == 0) {
#pragma unroll
        for (int ww = 0; ww < 3; ++ww)
#pragma unroll
            for (int s = 0; s < KNB; ++s)
                topk_insert(dumpV[(ww * 64 + l) * KNB + s],
                            dumpI[(ww * 64 + l) * KNB + s], bval, bidx);
        int row = i0 + l;
        size_t base = (size_t)row * (NSPLIT * KNB) + split * KNB;
#pragma unroll
        for (int s = 0; s < KNB; ++s) {
            cval[base + s] = bval[s];
            cidx[base + s] = bidx[s];
        }
    }
}

// ---------- 4) merge partial top-10s -> global top-10, build symmetric adjacency bitset ----------
__global__ __launch_bounds__(256) void merge_adj_kernel(
    const float* __restrict__ cval, const int* __restrict__ cidx,
    unsigned int* __restrict__ bits)
{
    int i = blockIdx.x * blockDim.x + threadIdx.x;
    if (i >= NN) return;
    float bval[KNB]; int bidx[KNB];
#pragma unroll
    for (int s = 0; s < KNB; ++s) { bval[s] = 3.0e38f; bidx[s] = 0x7fffffff; }
    for (int s = 0; s < NSPLIT * KNB; ++s) {
        float v = cval[(size_t)i * (NSPLIT * KNB) + s];
        int   j = cidx[(size_t)i * (NSPLIT * KNB) + s];
        topk_insert(v, j, bval, bidx);
    }
#pragma unroll
    for (int s = 0; s < KNB; ++s) {
        int j = bidx[s];
        atomicOr(&bits[(size_t)i * 256 + (j >> 5)], 1u << (j & 31));
        atomicOr(&bits[(size_t)j * 256 + (i >> 5)], 1u << (i & 31));
    }
}

// ---------- 5) label init ----------
__global__ __launch_bounds__(256) void labels_init_kernel(const int* __restrict__ slab, float* __restrict__ la)
{
    int tid = blockIdx.x * blockDim.x + threadIdx.x;   // NN*64 threads
    int i = tid >> 6, c = tid & 63;
    float v = 0.f;
    if (i < NS) v = (slab[i] == c) ? 1.f : 0.f;
    la[tid] = v;
}

// ---------- 6) one propagation step: lout[i] = sum_j (1/deg_i)*lin[j] over N(i), j ascending.
// Two-phase: ordered LDS edge list (shuffle prefix scan preserves ascending j ->
// identical fp32 sum order), then gather unrolled x4. Bitset-walk fallback if
// deg > PCAP (defensive; can't trigger at k=10).
__global__ __launch_bounds__(256) void prop_kernel(
    const unsigned int* __restrict__ bits, const float* __restrict__ lin, float* __restrict__ lout)
{
    __shared__ int lists[4][PCAP];
    const int grp = threadIdx.x >> 6;
    const int c   = threadIdx.x & 63;
    const int i   = blockIdx.x * 4 + grp;
    const unsigned int* row = bits + (size_t)i * 256;

    unsigned int mw[4];
#pragma unroll
    for (int k = 0; k < 4; ++k) mw[k] = row[4 * c + k];
    int cnt = __popc(mw[0]) + __popc(mw[1]) + __popc(mw[2]) + __popc(mw[3]);
    int incl = cnt;
#pragma unroll
    for (int d = 1; d < 64; d <<= 1) {
        int nb = __shfl_up(incl, d, 64);
        if (c >= d) incl += nb;
    }
    const int off = incl - cnt;
    const int deg = __shfl(incl, 63, 64);
    const bool use_list = (deg <= PCAP);

    if (use_list) {
        int p = off;
#pragma unroll
        for (int k = 0; k < 4; ++k) {
            unsigned int m = mw[k];
            while (m) {
                int b = __ffs(m) - 1;
                m &= m - 1;
                lists[grp][p++] = (4 * c + k) * 32 + b;
            }
        }
    }
    __syncthreads();

    const float tinv = 1.0f / (float)deg;          // deg >= 1 (self-loop)
    float acc = 0.f;
    if (use_list) {
        const int* lst = lists[grp];
        int d = 0;
        for (; d + 4 <= deg; d += 4) {
            int j0 = lst[d], j1 = lst[d + 1], j2 = lst[d + 2], j3 = lst[d + 3];
            float x0 = lin[(size_t)j0 * 64 + c];
            float x1 = lin[(size_t)j1 * 64 + c];
            float x2 = lin[(size_t)j2 * 64 + c];
            float x3 = lin[(size_t)j3 * 64 + c];
            acc += __fmul_rn(tinv, x0);
            acc += __fmul_rn(tinv, x1);
            acc += __fmul_rn(tinv, x2);
            acc += __fmul_rn(tinv, x3);
        }
        for (; d < deg; ++d) {
            int j = lst[d];
            acc += __fmul_rn(tinv, lin[(size_t)j * 64 + c]);
        }
    } else {
        for (int w2 = 0; w2 < 256; ++w2) {
            unsigned int m = row[w2];
            while (m) {
                int b = __ffs(m) - 1;
                m &= m - 1;
                int j = w2 * 32 + b;
                acc += __fmul_rn(tinv, lin[(size_t)j * 64 + c]);
            }
        }
    }
    lout[(size_t)i * 64 + c] = acc;
}

// ---------- 7) argmax (first-index tie-break) -> one-hot ----------
__global__ __launch_bounds__(256) void argmax_kernel(const float* __restrict__ labels, float* __restrict__ out)
{
    int q = blockIdx.x * 4 + (threadIdx.x >> 6);   // 0..NQ-1
    int c = threadIdx.x & 63;
    float bv = labels[(size_t)(NS + q) * 64 + c];
    int   bi = c;
#pragma unroll
    for (int off = 32; off >= 1; off >>= 1) {
        float ov = __shfl_xor(bv, off, 64);
        int   oi = __shfl_xor(bi, off, 64);
        if (ov > bv || (ov == bv && oi < bi)) { bv = ov; bi = oi; }
    }
    out[(size_t)q * 64 + c] = (c == bi) ? 1.0f : 0.0f;
}

// ---------- launch ----------
extern "C" void kernel_launch(void* const* d_in, const int* in_sizes, int n_in,
                              void* d_out, int out_size, void* d_ws, size_t ws_size,
                              hipStream_t stream)
{
    const float* support = (const float*)d_in[0];
    const float* query   = (const float*)d_in[1];
    const int*   slab    = (const int*)d_in[2];
    const float* W       = (const float*)d_in[3];
    float* out = (float*)d_out;
    char*  ws  = (char*)d_ws;

    // workspace (phase-aliased), total 13,664,256 B (fits proven ws):
    //   [0, 4M)      Ghi  -> bits [0,8M) after dist
    //   [4M, 8M)     Glo
    //   [8M, +32K)   sq (live through dist)
    //   [CV_OFF ...) sqpart (embed->sqsum) / cval (dist->merge) / la
    //   [CI_OFF ...) cidx (dist->merge) / lb
    const size_t GHI_OFF = 0;
    const size_t GLO_OFF = 4194304;
    const size_t SQ_OFF  = 8388608;
    const size_t CV_OFF  = 8421376;
    const size_t CI_OFF  = CV_OFF + (size_t)NN * NSPLIT * KNB * 4;   // +2,621,440

    bf16x8*       Ghi  = (bf16x8*)(ws + GHI_OFF);
    bf16x8*       Glo  = (bf16x8*)(ws + GLO_OFF);
    unsigned int* bits = (unsigned int*)(ws + GHI_OFF);   // aliases Ghi/Glo (dead after dist)
    float*        sq   = (float*)(ws + SQ_OFF);
    float*        sqp  = (float*)(ws + CV_OFF);           // aliases cval (dead before dist writes)
    float*        cval = (float*)(ws + CV_OFF);
    int*          cidx = (int*)  (ws + CI_OFF);
    float*        la   = (float*)(ws + CV_OFF);           // aliases cval (dead after merge)
    float*        lb   = (float*)(ws + CI_OFF);           // aliases cidx

    embed_kernel<<<dim3(128, 4), 256, 0, stream>>>(support, query, W, Ghi, Glo, sqp);
    sqsum_kernel<<<NN / 256, 256, 0, stream>>>(sqp, sq);
    dist_topk_kernel<<<dim3(128, NSPLIT), 256, 0, stream>>>(Ghi, Glo, sq, cval, cidx);
    hipMemsetAsync(bits, 0, (size_t)NN * 256 * sizeof(unsigned int), stream);   // Ghi/Glo dead
    merge_adj_kernel<<<NN / 256, 256, 0, stream>>>(cval, cidx, bits);
    labels_init_kernel<<<(NN * 64) / 256, 256, 0, stream>>>(slab, la);          // cval dead
    prop_kernel<<<NN / 4, 256, 0, stream>>>(bits, la, lb);
    prop_kernel<<<NN / 4, 256, 0, stream>>>(bits, lb, la);
    prop_kernel<<<NN / 4, 256, 0, stream>>>(bits, la, lb);
    argmax_kernel<<<NQ / 4, 256, 0, stream>>>(lb, out);
}

// Round 10
// 649.139 us; speedup vs baseline: 1.8030x; 1.1857x over previous
//
#include <hip/hip_runtime.h>
#include <stdint.h>

#define NS   2048
#define NQ   6144
#define NN   8192      // total nodes
#define IND  512
#define DM   256
#define KNB  10
#define NSPLIT 8
#define PCAP 1536      // prop edge-list capacity per node

typedef short bf16x8 __attribute__((ext_vector_type(8)));
typedef float f32x4  __attribute__((ext_vector_type(4)));
typedef unsigned long long u64;

// exact RNE fp32 -> bf16 (bits); bf16 exp range == fp32, no denormal hazard
__device__ __forceinline__ unsigned short f2bf(float v)
{
    unsigned int u = __float_as_uint(v);
    unsigned int r = (u + 0x7fffu + ((u >> 16) & 1u)) >> 16;
    return (unsigned short)r;
}
__device__ __forceinline__ float bf2f(unsigned short h)
{
    return __uint_as_float(((unsigned int)h) << 16);
}

// lexicographic (value, index) insert into sorted-ascending top-10 registers
__device__ __forceinline__ void topk_insert(float v, int j, float bval[KNB], int bidx[KNB])
{
    bool better = (v < bval[KNB-1]) || (v == bval[KNB-1] && j < bidx[KNB-1]);
    if (better) {
        float cv = v; int ci = j;
#pragma unroll
        for (int q = 0; q < KNB; ++q) {
            bool sw = (cv < bval[q]) || (cv == bval[q] && ci < bidx[q]);
            if (sw) {
                float tv = bval[q]; bval[q] = cv; cv = tv;
                int   ti = bidx[q]; bidx[q] = ci; ci = ti;
            }
        }
    }
}

// branchless 10-deep bubble insert of a u64 key (d2bits<<32 | j) into sorted-asc list
__device__ __forceinline__ void key_insert(u64 key, u64 K[KNB])
{
    u64 cur = key;
#pragma unroll
    for (int s = 0; s < KNB; ++s) {
        u64 lo = (cur < K[s]) ? cur : K[s];
        u64 hi = (cur < K[s]) ? K[s] : cur;
        K[s] = lo; cur = hi;
    }
}

// ---------- 1) embed: E = concat(support,query) @ W (8192x512x256), 64x64 tiles.
// grid 128x4 = 512 blocks = 2/CU. Per-output fp32 FMA order: k ascending.
// Epilogue packs E into MFMA-fragment-ordered bf16 hi/lo arrays
//   G[c][node][q][j]  (c=k/32, q=(k>>3)&3, j=k&7; 16 B per (node,q))
// and writes per-row partial squared norms (exact fp32 from acc).
__global__ __launch_bounds__(256) void embed_kernel(
    const float* __restrict__ support, const float* __restrict__ query,
    const float* __restrict__ W, bf16x8* __restrict__ Ghi, bf16x8* __restrict__ Glo,
    float* __restrict__ sqpart)
{
    __shared__ float smem[64 * 68];      // K-loop: A^T 32x68 | B 32x68 ; epilogue: Etile 64x68
    __shared__ float sqred[64 * 17];
    float* smemA = smem;
    float* smemB = smem + 32 * 68;
    const int t  = threadIdx.x;
    const int i0 = blockIdx.x * 64;
    const int n0 = blockIdx.y * 64;
    const int tx = t & 15, ty = t >> 4;

    float acc[4][4];
#pragma unroll
    for (int m = 0; m < 4; ++m)
#pragma unroll
        for (int n = 0; n < 4; ++n) acc[m][n] = 0.f;

    for (int kc = 0; kc < IND; kc += 32) {
        {   // A: rows i0..i0+64 of concat(support,query), cols kc..kc+32, transposed
            int a  = t >> 2;            // 0..63
            int cg = (t & 3) * 8;       // 0,8,16,24
            int g  = i0 + a;
            const float* src = (g < NS) ? (support + (size_t)g * IND)
                                        : (query + (size_t)(g - NS) * IND);
            src += kc + cg;
#pragma unroll
            for (int q = 0; q < 2; ++q) {
                float4 v = *reinterpret_cast<const float4*>(src + q * 4);
                smemA[(cg + q*4 + 0) * 68 + a] = v.x;
                smemA[(cg + q*4 + 1) * 68 + a] = v.y;
                smemA[(cg + q*4 + 2) * 68 + a] = v.z;
                smemA[(cg + q*4 + 3) * 68 + a] = v.w;
            }
        }
        {   // B: W rows kc..kc+32, cols n0..n0+64 (k-major)
            int r  = t >> 3;            // 0..31
            int cg = (t & 7) * 8;       // 0..56
            const float* src = W + (size_t)(kc + r) * DM + n0 + cg;
#pragma unroll
            for (int q = 0; q < 2; ++q) {
                float4 v = *reinterpret_cast<const float4*>(src + q * 4);
                *reinterpret_cast<float4*>(&smemB[r * 68 + cg + q * 4]) = v;
            }
        }
        __syncthreads();
#pragma unroll
        for (int kk = 0; kk < 32; ++kk) {
            float4 a0 = *reinterpret_cast<const float4*>(&smemA[kk * 68 + ty * 4]);
            float4 b0 = *reinterpret_cast<const float4*>(&smemB[kk * 68 + tx * 4]);
            float af[4] = {a0.x, a0.y, a0.z, a0.w};
            float bf[4] = {b0.x, b0.y, b0.z, b0.w};
#pragma unroll
            for (int m = 0; m < 4; ++m)
#pragma unroll
                for (int n = 0; n < 4; ++n)
                    acc[m][n] += af[m] * bf[n];
        }
        __syncthreads();
    }
    // epilogue: partial row norms + stage E tile to LDS (smemA/B dead), pack bf16 hi/lo
#pragma unroll
    for (int m = 0; m < 4; ++m) {
        float s = 0.f;
#pragma unroll
        for (int n = 0; n < 4; ++n) {
            float v = acc[m][n];
            s += v * v;
            smem[(ty * 4 + m) * 68 + tx * 4 + n] = v;
        }
        sqred[(ty * 4 + m) * 17 + tx] = s;
    }
    __syncthreads();
#pragma unroll
    for (int e = 0; e < 2; ++e) {
        int g  = t * 2 + e;              // 0..511 = 64 rows x 2 chunks x 4 quads
        int rl = g >> 3;
        int ch = (g >> 2) & 1;
        int qq = g & 3;
        const float* ep = &smem[rl * 68 + ch * 32 + qq * 8];
        bf16x8 h8, l8;
#pragma unroll
        for (int jj = 0; jj < 8; ++jj) {
            float v = ep[jj];
            unsigned short hu = f2bf(v);
            float hf = bf2f(hu);
            unsigned short lu = f2bf(v - hf);
            h8[jj] = (short)hu;
            l8[jj] = (short)lu;
        }
        int cc = blockIdx.y * 2 + ch;
        size_t gi = ((size_t)cc * NN + i0 + rl) * 4 + qq;
        Ghi[gi] = h8;
        Glo[gi] = l8;
    }
    if (t < 64) {
        float s = 0.f;
#pragma unroll
        for (int x = 0; x < 16; ++x) s += sqred[t * 17 + x];
        sqpart[(size_t)blockIdx.y * NN + i0 + t] = s;
    }
}

// ---------- 2) combine the four column-quarter partial norms ----------
__global__ __launch_bounds__(256) void sqsum_kernel(const float* __restrict__ sqpart,
                                                    float* __restrict__ sq)
{
    int i = blockIdx.x * 256 + threadIdx.x;
    sq[i] = ((sqpart[i] + sqpart[NN + i]) + sqpart[2 * NN + i]) + sqpart[3 * NN + i];
}

// ---------- 3) fused distance MFMA-GEMM + streaming per-row top-10 ----------
// Same structure as r9 (operands flipped so lane&15 == row; per-lane LDS candidate
// stacks; predicated push; ballot-bounded drains), PLUS the missing __syncthreads()
// before the final dump: the dump region (linear t*10+s) ALIASES OTHER WAVES'
// slot-major stack slots, so all waves must finish their jt loops before any wave
// dumps (this race was r9's absmax-1.0 failure). One barrier per kernel total.
// Block: 256 thr = 4 waves x 16 rows; 64 rows x 128-col tiles; grid 128x8 = 1024.
__global__ __launch_bounds__(256) void dist_topk_kernel(
    const bf16x8* __restrict__ Ghi, const bf16x8* __restrict__ Glo,
    const float* __restrict__ sq, float* __restrict__ cval, int* __restrict__ cidx)
{
    __shared__ u64 stk[12][256];                 // 24576 B, slot-major per-thread stacks
    const int t  = threadIdx.x;
    const int l  = t & 63, w = t >> 6;
    const int lm = l & 15, q = l >> 4;
    const int i0 = blockIdx.x * 64;
    const int row = i0 + 16 * w + lm;            // this lane's row
    const int split = blockIdx.y;

    const float  sqi   = sq[row];
    const size_t rBase = (size_t)row * 4 + q;    // row-frag index (bf16x8 units)

    u64 K[KNB];
#pragma unroll
    for (int s = 0; s < KNB; ++s) K[s] = ~0ull;
    u64 thr = ~0ull;
    int cnt = 0;

    auto drain = [&]() {
        u64 live = __ballot(cnt > 0);
        while (live) {
            if (cnt > 0) {
                --cnt;
                u64 key = stk[cnt][t];
                if (key < thr) {
                    key_insert(key, K);
                    thr = K[KNB - 1];
                }
            }
            live = __ballot(cnt > 0);
        }
    };

    for (int jt = 0; jt < 8; ++jt) {
        const int j0 = split * 1024 + jt * 128;
        const size_t cBase = (size_t)(j0 + lm) * 4 + q;   // col-frag base (mt=0)

        f32x4 acc[8];
#pragma unroll
        for (int mt = 0; mt < 8; ++mt) acc[mt] = (f32x4){0.f, 0.f, 0.f, 0.f};

        for (int c = 0; c < 8; ++c) {
            const size_t co = (size_t)c * (NN * 4);
            const bf16x8 Bh = Ghi[rBase + co];
            const bf16x8 Bl = Glo[rBase + co];
            // two base pointers keep all col-frag offsets within the 13-bit imm
            const bf16x8* pH0 = Ghi + cBase + co;
            const bf16x8* pH1 = pH0 + 256;
            const bf16x8* pL0 = Glo + cBase + co;
            const bf16x8* pL1 = pL0 + 256;
#pragma unroll
            for (int mt = 0; mt < 8; ++mt) {
                const bf16x8 Ah = (mt < 4) ? pH0[mt * 64] : pH1[(mt - 4) * 64];
                const bf16x8 Al = (mt < 4) ? pL0[mt * 64] : pL1[(mt - 4) * 64];
                f32x4 a = acc[mt];
                a = __builtin_amdgcn_mfma_f32_16x16x32_bf16(Ah, Bh, a, 0, 0, 0);
                a = __builtin_amdgcn_mfma_f32_16x16x32_bf16(Ah, Bl, a, 0, 0, 0);
                a = __builtin_amdgcn_mfma_f32_16x16x32_bf16(Al, Bh, a, 0, 0, 0);
                a = __builtin_amdgcn_mfma_f32_16x16x32_bf16(Al, Bl, a, 0, 0, 0);
                acc[mt] = a;
            }
        }
        // epilogue: d2 directly from registers; predicated stack push per element
#pragma unroll
        for (int mt = 0; mt < 8; ++mt) {
            const int jb = j0 + 16 * mt + 4 * q;
            const f32x4 sqj = *reinterpret_cast<const f32x4*>(&sq[jb]);
#pragma unroll
            for (int r = 0; r < 4; ++r) {
                float d2 = fmaxf(sqi + sqj[r] - 2.0f * acc[mt][r], 0.0f);
                u64 key = ((u64)__float_as_uint(d2) << 32) | (unsigned)(jb + r);
                if (key < thr) { stk[cnt][t] = key; ++cnt; }
            }
            if (__any(cnt > 8)) drain();     // cap guard: <=4 pushes per mt, cap 12
        }
        drain();
    }
    // cross-q merge (4 lanes of the same wave share a row). The dump region
    // linearly re-indexes stk and thus aliases OTHER waves' stack slots ->
    // MUST barrier so every wave has finished (and drained) before any dump.
    __syncthreads();
    u64* dump = &stk[0][0];                      // 256 x 10 u64 = 20480 B <= 24576
#pragma unroll
    for (int s = 0; s < KNB; ++s) dump[t * KNB + s] = K[s];
    if (q == 0) {
#pragma unroll
        for (int qq = 1; qq < 4; ++qq)
#pragma unroll
            for (int s = 0; s < KNB; ++s) {
                u64 key = dump[(t + qq * 16) * KNB + s];
                if (key < thr) {
                    key_insert(key, K);
                    thr = K[KNB - 1];
                }
            }
        size_t base = (size_t)row * (NSPLIT * KNB) + split * KNB;
#pragma unroll
        for (int s = 0; s < KNB; ++s) {
            cval[base + s] = __uint_as_float((unsigned)(K[s] >> 32));
            cidx[base + s] = (int)(K[s] & 0xFFFFFFFFu);
        }
    }
}

// ---------- 4) merge partial top-10s -> global top-10, build symmetric adjacency bitset ----------
__global__ __launch_bounds__(256) void merge_adj_kernel(
    const float* __restrict__ cval, const int* __restrict__ cidx,
    unsigned int* __restrict__ bits)
{
    int i = blockIdx.x * blockDim.x + threadIdx.x;
    if (i >= NN) return;
    float bval[KNB]; int bidx[KNB];
#pragma unroll
    for (int s = 0; s < KNB; ++s) { bval[s] = 3.0e38f; bidx[s] = 0x7fffffff; }
    for (int s = 0; s < NSPLIT * KNB; ++s) {
        float v = cval[(size_t)i * (NSPLIT * KNB) + s];
        int   j = cidx[(size_t)i * (NSPLIT * KNB) + s];
        topk_insert(v, j, bval, bidx);
    }
#pragma unroll
    for (int s = 0; s < KNB; ++s) {
        int j = bidx[s];
        atomicOr(&bits[(size_t)i * 256 + (j >> 5)], 1u << (j & 31));
        atomicOr(&bits[(size_t)j * 256 + (i >> 5)], 1u << (i & 31));
    }
}

// ---------- 5) label init ----------
__global__ __launch_bounds__(256) void labels_init_kernel(const int* __restrict__ slab, float* __restrict__ la)
{
    int tid = blockIdx.x * blockDim.x + threadIdx.x;   // NN*64 threads
    int i = tid >> 6, c = tid & 63;
    float v = 0.f;
    if (i < NS) v = (slab[i] == c) ? 1.f : 0.f;
    la[tid] = v;
}

// ---------- 6) one propagation step: lout[i] = sum_j (1/deg_i)*lin[j] over N(i), j ascending.
__global__ __launch_bounds__(256) void prop_kernel(
    const unsigned int* __restrict__ bits, const float* __restrict__ lin, float* __restrict__ lout)
{
    __shared__ int lists[4][PCAP];
    const int grp = threadIdx.x >> 6;
    const int c   = threadIdx.x & 63;
    const int i   = blockIdx.x * 4 + grp;
    const unsigned int* row = bits + (size_t)i * 256;

    unsigned int mw[4];
#pragma unroll
    for (int k = 0; k < 4; ++k) mw[k] = row[4 * c + k];
    int cnt = __popc(mw[0]) + __popc(mw[1]) + __popc(mw[2]) + __popc(mw[3]);
    int incl = cnt;
#pragma unroll
    for (int d = 1; d < 64; d <<= 1) {
        int nb = __shfl_up(incl, d, 64);
        if (c >= d) incl += nb;
    }
    const int off = incl - cnt;
    const int deg = __shfl(incl, 63, 64);
    const bool use_list = (deg <= PCAP);

    if (use_list) {
        int p = off;
#pragma unroll
        for (int k = 0; k < 4; ++k) {
            unsigned int m = mw[k];
            while (m) {
                int b = __ffs(m) - 1;
                m &= m - 1;
                lists[grp][p++] = (4 * c + k) * 32 + b;
            }
        }
    }
    __syncthreads();

    const float tinv = 1.0f / (float)deg;          // deg >= 1 (self-loop)
    float acc = 0.f;
    if (use_list) {
        const int* lst = lists[grp];
        int d = 0;
        for (; d + 4 <= deg; d += 4) {
            int j0 = lst[d], j1 = lst[d + 1], j2 = lst[d + 2], j3 = lst[d + 3];
            float x0 = lin[(size_t)j0 * 64 + c];
            float x1 = lin[(size_t)j1 * 64 + c];
            float x2 = lin[(size_t)j2 * 64 + c];
            float x3 = lin[(size_t)j3 * 64 + c];
            acc += __fmul_rn(tinv, x0);
            acc += __fmul_rn(tinv, x1);
            acc += __fmul_rn(tinv, x2);
            acc += __fmul_rn(tinv, x3);
        }
        for (; d < deg; ++d) {
            int j = lst[d];
            acc += __fmul_rn(tinv, lin[(size_t)j * 64 + c]);
        }
    } else {
        for (int w2 = 0; w2 < 256; ++w2) {
            unsigned int m = row[w2];
            while (m) {
                int b = __ffs(m) - 1;
                m &= m - 1;
                int j = w2 * 32 + b;
                acc += __fmul_rn(tinv, lin[(size_t)j * 64 + c]);
            }
        }
    }
    lout[(size_t)i * 64 + c] = acc;
}

// ---------- 7) argmax (first-index tie-break) -> one-hot ----------
__global__ __launch_bounds__(256) void argmax_kernel(const float* __restrict__ labels, float* __restrict__ out)
{
    int q = blockIdx.x * 4 + (threadIdx.x >> 6);   // 0..NQ-1
    int c = threadIdx.x & 63;
    float bv = labels[(size_t)(NS + q) * 64 + c];
    int   bi = c;
#pragma unroll
    for (int off = 32; off >= 1; off >>= 1) {
        float ov = __shfl_xor(bv, off, 64);
        int   oi = __shfl_xor(bi, off, 64);
        if (ov > bv || (ov == bv && oi < bi)) { bv = ov; bi = oi; }
    }
    out[(size_t)q * 64 + c] = (c == bi) ? 1.0f : 0.0f;
}

// ---------- launch ----------
extern "C" void kernel_launch(void* const* d_in, const int* in_sizes, int n_in,
                              void* d_out, int out_size, void* d_ws, size_t ws_size,
                              hipStream_t stream)
{
    const float* support = (const float*)d_in[0];
    const float* query   = (const float*)d_in[1];
    const int*   slab    = (const int*)d_in[2];
    const float* W       = (const float*)d_in[3];
    float* out = (float*)d_out;
    char*  ws  = (char*)d_ws;

    // workspace (phase-aliased), total 13,664,256 B:
    //   [0, 4M)      Ghi  -> bits [0,8M) after dist
    //   [4M, 8M)     Glo
    //   [8M, +32K)   sq (live through dist)
    //   [CV_OFF ...) sqpart (embed->sqsum) / cval (dist->merge) / la
    //   [CI_OFF ...) cidx (dist->merge) / lb
    const size_t GHI_OFF = 0;
    const size_t GLO_OFF = 4194304;
    const size_t SQ_OFF  = 8388608;
    const size_t CV_OFF  = 8421376;
    const size_t CI_OFF  = CV_OFF + (size_t)NN * NSPLIT * KNB * 4;   // +2,621,440

    bf16x8*       Ghi  = (bf16x8*)(ws + GHI_OFF);
    bf16x8*       Glo  = (bf16x8*)(ws + GLO_OFF);
    unsigned int* bits = (unsigned int*)(ws + GHI_OFF);   // aliases Ghi/Glo (dead after dist)
    float*        sq   = (float*)(ws + SQ_OFF);
    float*        sqp  = (float*)(ws + CV_OFF);           // aliases cval (dead before dist writes)
    float*        cval = (float*)(ws + CV_OFF);
    int*          cidx = (int*)  (ws + CI_OFF);
    float*        la   = (float*)(ws + CV_OFF);           // aliases cval (dead after merge)
    float*        lb   = (float*)(ws + CI_OFF);           // aliases cidx

    embed_kernel<<<dim3(128, 4), 256, 0, stream>>>(support, query, W, Ghi, Glo, sqp);
    sqsum_kernel<<<NN / 256, 256, 0, stream>>>(sqp, sq);
    dist_topk_kernel<<<dim3(128, NSPLIT), 256, 0, stream>>>(Ghi, Glo, sq, cval, cidx);
    hipMemsetAsync(bits, 0, (size_t)NN * 256 * sizeof(unsigned int), stream);   // Ghi/Glo dead
    merge_adj_kernel<<<NN / 256, 256, 0, stream>>>(cval, cidx, bits);
    labels_init_kernel<<<(NN * 64) / 256, 256, 0, stream>>>(slab, la);          // cval dead
    prop_kernel<<<NN / 4, 256, 0, stream>>>(bits, la, lb);
    prop_kernel<<<NN / 4, 256, 0, stream>>>(bits, lb, la);
    prop_kernel<<<NN / 4, 256, 0, stream>>>(bits, la, lb);
    argmax_kernel<<<NQ / 4, 256, 0, stream>>>(lb, out);
}

// Round 11
// 492.833 us; speedup vs baseline: 2.3748x; 1.3172x over previous
//
#include <hip/hip_runtime.h>
#include <stdint.h>

#define NS   2048
#define NQ   6144
#define NN   8192      // total nodes
#define IND  512
#define DM   256
#define KNB  10
#define NSPLIT 8
#define PCAP 1536      // prop edge-list capacity per node

#define AS1 __attribute__((address_space(1)))
#define AS3 __attribute__((address_space(3)))

typedef short bf16x8 __attribute__((ext_vector_type(8)));
typedef float f32x4  __attribute__((ext_vector_type(4)));
typedef unsigned long long u64;

// exact RNE fp32 -> bf16 (bits); bf16 exp range == fp32, no denormal hazard
__device__ __forceinline__ unsigned short f2bf(float v)
{
    unsigned int u = __float_as_uint(v);
    unsigned int r = (u + 0x7fffu + ((u >> 16) & 1u)) >> 16;
    return (unsigned short)r;
}
__device__ __forceinline__ float bf2f(unsigned short h)
{
    return __uint_as_float(((unsigned int)h) << 16);
}

// lexicographic (value, index) insert into sorted-ascending top-10 registers
__device__ __forceinline__ void topk_insert(float v, int j, float bval[KNB], int bidx[KNB])
{
    bool better = (v < bval[KNB-1]) || (v == bval[KNB-1] && j < bidx[KNB-1]);
    if (better) {
        float cv = v; int ci = j;
#pragma unroll
        for (int q = 0; q < KNB; ++q) {
            bool sw = (cv < bval[q]) || (cv == bval[q] && ci < bidx[q]);
            if (sw) {
                float tv = bval[q]; bval[q] = cv; cv = tv;
                int   ti = bidx[q]; bidx[q] = ci; ci = ti;
            }
        }
    }
}

// branchless 10-deep bubble insert of a u64 key (d2bits<<32 | j) into sorted-asc list
__device__ __forceinline__ void key_insert(u64 key, u64 K[KNB])
{
    u64 cur = key;
#pragma unroll
    for (int s = 0; s < KNB; ++s) {
        u64 lo = (cur < K[s]) ? cur : K[s];
        u64 hi = (cur < K[s]) ? K[s] : cur;
        K[s] = lo; cur = hi;
    }
}

// ---------- 1) embed: E = concat(support,query) @ W (8192x512x256), 64x64 tiles.
// grid 128x4 = 512 blocks = 2/CU. Per-output fp32 FMA order: k ascending.
// Epilogue packs E into MFMA-fragment-ordered bf16 hi/lo arrays
//   G[c][node][q][j]  (c=k/32, q=(k>>3)&3, j=k&7; 16 B per (node,q))
// and writes per-row partial squared norms (exact fp32 from acc).
__global__ __launch_bounds__(256) void embed_kernel(
    const float* __restrict__ support, const float* __restrict__ query,
    const float* __restrict__ W, bf16x8* __restrict__ Ghi, bf16x8* __restrict__ Glo,
    float* __restrict__ sqpart)
{
    __shared__ float smem[64 * 68];      // K-loop: A^T 32x68 | B 32x68 ; epilogue: Etile 64x68
    __shared__ float sqred[64 * 17];
    float* smemA = smem;
    float* smemB = smem + 32 * 68;
    const int t  = threadIdx.x;
    const int i0 = blockIdx.x * 64;
    const int n0 = blockIdx.y * 64;
    const int tx = t & 15, ty = t >> 4;

    float acc[4][4];
#pragma unroll
    for (int m = 0; m < 4; ++m)
#pragma unroll
        for (int n = 0; n < 4; ++n) acc[m][n] = 0.f;

    for (int kc = 0; kc < IND; kc += 32) {
        {   // A: rows i0..i0+64 of concat(support,query), cols kc..kc+32, transposed
            int a  = t >> 2;            // 0..63
            int cg = (t & 3) * 8;       // 0,8,16,24
            int g  = i0 + a;
            const float* src = (g < NS) ? (support + (size_t)g * IND)
                                        : (query + (size_t)(g - NS) * IND);
            src += kc + cg;
#pragma unroll
            for (int q = 0; q < 2; ++q) {
                float4 v = *reinterpret_cast<const float4*>(src + q * 4);
                smemA[(cg + q*4 + 0) * 68 + a] = v.x;
                smemA[(cg + q*4 + 1) * 68 + a] = v.y;
                smemA[(cg + q*4 + 2) * 68 + a] = v.z;
                smemA[(cg + q*4 + 3) * 68 + a] = v.w;
            }
        }
        {   // B: W rows kc..kc+32, cols n0..n0+64 (k-major)
            int r  = t >> 3;            // 0..31
            int cg = (t & 7) * 8;       // 0..56
            const float* src = W + (size_t)(kc + r) * DM + n0 + cg;
#pragma unroll
            for (int q = 0; q < 2; ++q) {
                float4 v = *reinterpret_cast<const float4*>(src + q * 4);
                *reinterpret_cast<float4*>(&smemB[r * 68 + cg + q * 4]) = v;
            }
        }
        __syncthreads();
#pragma unroll
        for (int kk = 0; kk < 32; ++kk) {
            float4 a0 = *reinterpret_cast<const float4*>(&smemA[kk * 68 + ty * 4]);
            float4 b0 = *reinterpret_cast<const float4*>(&smemB[kk * 68 + tx * 4]);
            float af[4] = {a0.x, a0.y, a0.z, a0.w};
            float bf[4] = {b0.x, b0.y, b0.z, b0.w};
#pragma unroll
            for (int m = 0; m < 4; ++m)
#pragma unroll
                for (int n = 0; n < 4; ++n)
                    acc[m][n] += af[m] * bf[n];
        }
        __syncthreads();
    }
    // epilogue: partial row norms + stage E tile to LDS (smemA/B dead), pack bf16 hi/lo
#pragma unroll
    for (int m = 0; m < 4; ++m) {
        float s = 0.f;
#pragma unroll
        for (int n = 0; n < 4; ++n) {
            float v = acc[m][n];
            s += v * v;
            smem[(ty * 4 + m) * 68 + tx * 4 + n] = v;
        }
        sqred[(ty * 4 + m) * 17 + tx] = s;
    }
    __syncthreads();
#pragma unroll
    for (int e = 0; e < 2; ++e) {
        int g  = t * 2 + e;              // 0..511 = 64 rows x 2 chunks x 4 quads
        int rl = g >> 3;
        int ch = (g >> 2) & 1;
        int qq = g & 3;
        const float* ep = &smem[rl * 68 + ch * 32 + qq * 8];
        bf16x8 h8, l8;
#pragma unroll
        for (int jj = 0; jj < 8; ++jj) {
            float v = ep[jj];
            unsigned short hu = f2bf(v);
            float hf = bf2f(hu);
            unsigned short lu = f2bf(v - hf);
            h8[jj] = (short)hu;
            l8[jj] = (short)lu;
        }
        int cc = blockIdx.y * 2 + ch;
        size_t gi = ((size_t)cc * NN + i0 + rl) * 4 + qq;
        Ghi[gi] = h8;
        Glo[gi] = l8;
    }
    if (t < 64) {
        float s = 0.f;
#pragma unroll
        for (int x = 0; x < 16; ++x) s += sqred[t * 17 + x];
        sqpart[(size_t)blockIdx.y * NN + i0 + t] = s;
    }
}

// ---------- 2) combine the four column-quarter partial norms ----------
__global__ __launch_bounds__(256) void sqsum_kernel(const float* __restrict__ sqpart,
                                                    float* __restrict__ sq)
{
    int i = blockIdx.x * 256 + threadIdx.x;
    sq[i] = ((sqpart[i] + sqpart[NN + i]) + sqpart[2 * NN + i]) + sqpart[3 * NN + i];
}

// ---------- 3) fused distance MFMA-GEMM + streaming per-row top-10 ----------
// r10 was bound by redundant col-fragment loads (all 4 waves load the same 128-col
// tile -> 4.2 GB L2/L3 traffic vs 4 MB per-XCD L2). This version stages the col
// tile in LDS ONCE per block via global_load_lds (width 16, m97 pattern):
//  * col frags of a 128-col tile are CONTIGUOUS in G ((j0+col)*4+q spans 512
//    consecutive frags), so the wave-uniform-base + lane*16 constraint is met
//    with plain linear staging: wave w stages frags [256w, 256w+256) in 4 issues.
//  * double-buffered over the 64 flattened (jt,c) iterations; ONE barrier/iter
//    (the __syncthreads vmcnt drain completes the async stage of iter+1).
//  * consumers ds_read_b128 a contiguous-permuted 1 KB region per mt (optimal).
//  * per-lane candidate stacks shrink to depth 4 (drained after every mt).
// LDS = 32 KB stage + 8 KB stacks = 40960 B -> 4 blocks/CU. Grid 128x8 = 1024.
// Operand-flipped MFMA (lane&15 == row) + u64-key stacks validated in r10.
__global__ __launch_bounds__(256) void dist_topk_kernel(
    const bf16x8* __restrict__ Ghi, const bf16x8* __restrict__ Glo,
    const float* __restrict__ sq, float* __restrict__ cval, int* __restrict__ cidx)
{
    __shared__ bf16x8 stage[2][1024];            // 2 x 16 KB: [0,512)=hi, [512,1024)=lo
    __shared__ u64 stk[4][256];                  // 8 KB, slot-major per-thread stacks
    const int t  = threadIdx.x;
    const int l  = t & 63, w = t >> 6;
    const int lm = l & 15, q = l >> 4;
    const int i0 = blockIdx.x * 64;
    const int row = i0 + 16 * w + lm;            // this lane's row
    const int split = blockIdx.y;

    const float  sqi   = sq[row];
    const size_t rBase = (size_t)row * 4 + q;    // row-frag index (bf16x8 units)

    u64 K[KNB];
#pragma unroll
    for (int s = 0; s < KNB; ++s) K[s] = ~0ull;
    u64 thr = ~0ull;
    int cnt = 0;

    auto drain = [&]() {
        u64 live = __ballot(cnt > 0);
        while (live) {
            if (cnt > 0) {
                --cnt;
                u64 key = stk[cnt][t];
                if (key < thr) {
                    key_insert(key, K);
                    thr = K[KNB - 1];
                }
            }
            live = __ballot(cnt > 0);
        }
    };

    // async-stage the col tile for flattened iteration it (jt=it>>3, c=it&7) into buf b.
    // wave w covers frags [256w, 256w+256): w<2 -> hi, w>=2 -> lo. LDS dst is
    // wave-uniform; HW adds lane*16.
    auto stage_issue = [&](int it, int b) {
        const int jt = split * 8 + (it >> 3);
        const int c  = it & 7;
        const size_t gbase = (size_t)(jt * 128) * 4 + (size_t)c * (NN * 4);
        const int fb0 = w * 256;
        const bf16x8* gsrc = (w < 2) ? (Ghi + gbase + fb0) : (Glo + gbase + (fb0 - 512));
#pragma unroll
        for (int u = 0; u < 4; ++u) {
            const bf16x8* g = gsrc + u * 64 + l;
            __builtin_amdgcn_global_load_lds((const AS1 void*)g,
                                             (AS3 void*)&stage[b][fb0 + u * 64],
                                             16, 0, 0);
        }
    };

    stage_issue(0, 0);
    __syncthreads();                             // drains vmcnt -> stage 0 resident

    f32x4 acc[8];
    for (int it = 0; it < 64; ++it) {
        const int c = it & 7;
        const int b = it & 1;
        if (it + 1 < 64) stage_issue(it + 1, (it + 1) & 1);
        if (c == 0) {
#pragma unroll
            for (int mt = 0; mt < 8; ++mt) acc[mt] = (f32x4){0.f, 0.f, 0.f, 0.f};
        }
        const size_t co = (size_t)c * (NN * 4);
        const bf16x8 Bh = Ghi[rBase + co];       // row frags: tiny working set, L1/L2-hit
        const bf16x8 Bl = Glo[rBase + co];
        const bf16x8* sh = &stage[b][0];
        const bf16x8* sl = &stage[b][512];
#pragma unroll
        for (int mt = 0; mt < 8; ++mt) {
            const int fi = (16 * mt + lm) * 4 + q;
            const bf16x8 Ah = sh[fi];
            const bf16x8 Al = sl[fi];
            f32x4 a = acc[mt];
            a = __builtin_amdgcn_mfma_f32_16x16x32_bf16(Ah, Bh, a, 0, 0, 0);
            a = __builtin_amdgcn_mfma_f32_16x16x32_bf16(Ah, Bl, a, 0, 0, 0);
            a = __builtin_amdgcn_mfma_f32_16x16x32_bf16(Al, Bh, a, 0, 0, 0);
            a = __builtin_amdgcn_mfma_f32_16x16x32_bf16(Al, Bl, a, 0, 0, 0);
            acc[mt] = a;
        }
        if (c == 7) {
            // per-jt epilogue: d2 from registers; predicated push; drain per mt
            const int j0 = split * 1024 + (it >> 3) * 128;
#pragma unroll
            for (int mt = 0; mt < 8; ++mt) {
                const int jb = j0 + 16 * mt + 4 * q;
                const f32x4 sqj = *reinterpret_cast<const f32x4*>(&sq[jb]);
#pragma unroll
                for (int r = 0; r < 4; ++r) {
                    float d2 = fmaxf(sqi + sqj[r] - 2.0f * acc[mt][r], 0.0f);
                    u64 key = ((u64)__float_as_uint(d2) << 32) | (unsigned)(jb + r);
                    if (key < thr) { stk[cnt][t] = key; ++cnt; }   // cnt <= 3 (depth 4)
                }
                drain();                          // empties stack; cheap when empty
            }
        }
        __syncthreads();   // consumers done with buf b; stage of it+1 drained (vmcnt)
    }
    // cross-q merge (4 lanes of a wave share a row). Dump region reuses the stage
    // buffers (all compute finished at the loop's final barrier). Same-wave
    // write->read needs only lgkmcnt (compiler-inserted).
    u64* dump = reinterpret_cast<u64*>(&stage[0][0]);    // 256*10*8 B = 20480 <= 32768
#pragma unroll
    for (int s = 0; s < KNB; ++s) dump[t * KNB + s] = K[s];
    if (q == 0) {
#pragma unroll
        for (int qq = 1; qq < 4; ++qq)
#pragma unroll
            for (int s = 0; s < KNB; ++s) {
                u64 key = dump[(t + qq * 16) * KNB + s];
                if (key < thr) {
                    key_insert(key, K);
                    thr = K[KNB - 1];
                }
            }
        size_t base = (size_t)row * (NSPLIT * KNB) + split * KNB;
#pragma unroll
        for (int s = 0; s < KNB; ++s) {
            cval[base + s] = __uint_as_float((unsigned)(K[s] >> 32));
            cidx[base + s] = (int)(K[s] & 0xFFFFFFFFu);
        }
    }
}

// ---------- 4) merge partial top-10s -> global top-10, build symmetric adjacency bitset ----------
__global__ __launch_bounds__(256) void merge_adj_kernel(
    const float* __restrict__ cval, const int* __restrict__ cidx,
    unsigned int* __restrict__ bits)
{
    int i = blockIdx.x * blockDim.x + threadIdx.x;
    if (i >= NN) return;
    float bval[KNB]; int bidx[KNB];
#pragma unroll
    for (int s = 0; s < KNB; ++s) { bval[s] = 3.0e38f; bidx[s] = 0x7fffffff; }
    for (int s = 0; s < NSPLIT * KNB; ++s) {
        float v = cval[(size_t)i * (NSPLIT * KNB) + s];
        int   j = cidx[(size_t)i * (NSPLIT * KNB) + s];
        topk_insert(v, j, bval, bidx);
    }
#pragma unroll
    for (int s = 0; s < KNB; ++s) {
        int j = bidx[s];
        atomicOr(&bits[(size_t)i * 256 + (j >> 5)], 1u << (j & 31));
        atomicOr(&bits[(size_t)j * 256 + (i >> 5)], 1u << (i & 31));
    }
}

// ---------- 5) label init ----------
__global__ __launch_bounds__(256) void labels_init_kernel(const int* __restrict__ slab, float* __restrict__ la)
{
    int tid = blockIdx.x * blockDim.x + threadIdx.x;   // NN*64 threads
    int i = tid >> 6, c = tid & 63;
    float v = 0.f;
    if (i < NS) v = (slab[i] == c) ? 1.f : 0.f;
    la[tid] = v;
}

// ---------- 6) one propagation step: lout[i] = sum_j (1/deg_i)*lin[j] over N(i), j ascending.
__global__ __launch_bounds__(256) void prop_kernel(
    const unsigned int* __restrict__ bits, const float* __restrict__ lin, float* __restrict__ lout)
{
    __shared__ int lists[4][PCAP];
    const int grp = threadIdx.x >> 6;
    const int c   = threadIdx.x & 63;
    const int i   = blockIdx.x * 4 + grp;
    const unsigned int* row = bits + (size_t)i * 256;

    unsigned int mw[4];
#pragma unroll
    for (int k = 0; k < 4; ++k) mw[k] = row[4 * c + k];
    int cnt = __popc(mw[0]) + __popc(mw[1]) + __popc(mw[2]) + __popc(mw[3]);
    int incl = cnt;
#pragma unroll
    for (int d = 1; d < 64; d <<= 1) {
        int nb = __shfl_up(incl, d, 64);
        if (c >= d) incl += nb;
    }
    const int off = incl - cnt;
    const int deg = __shfl(incl, 63, 64);
    const bool use_list = (deg <= PCAP);

    if (use_list) {
        int p = off;
#pragma unroll
        for (int k = 0; k < 4; ++k) {
            unsigned int m = mw[k];
            while (m) {
                int b = __ffs(m) - 1;
                m &= m - 1;
                lists[grp][p++] = (4 * c + k) * 32 + b;
            }
        }
    }
    __syncthreads();

    const float tinv = 1.0f / (float)deg;          // deg >= 1 (self-loop)
    float acc = 0.f;
    if (use_list) {
        const int* lst = lists[grp];
        int d = 0;
        for (; d + 4 <= deg; d += 4) {
            int j0 = lst[d], j1 = lst[d + 1], j2 = lst[d + 2], j3 = lst[d + 3];
            float x0 = lin[(size_t)j0 * 64 + c];
            float x1 = lin[(size_t)j1 * 64 + c];
            float x2 = lin[(size_t)j2 * 64 + c];
            float x3 = lin[(size_t)j3 * 64 + c];
            acc += __fmul_rn(tinv, x0);
            acc += __fmul_rn(tinv, x1);
            acc += __fmul_rn(tinv, x2);
            acc += __fmul_rn(tinv, x3);
        }
        for (; d < deg; ++d) {
            int j = lst[d];
            acc += __fmul_rn(tinv, lin[(size_t)j * 64 + c]);
        }
    } else {
        for (int w2 = 0; w2 < 256; ++w2) {
            unsigned int m = row[w2];
            while (m) {
                int b = __ffs(m) - 1;
                m &= m - 1;
                int j = w2 * 32 + b;
                acc += __fmul_rn(tinv, lin[(size_t)j * 64 + c]);
            }
        }
    }
    lout[(size_t)i * 64 + c] = acc;
}

// ---------- 7) argmax (first-index tie-break) -> one-hot ----------
__global__ __launch_bounds__(256) void argmax_kernel(const float* __restrict__ labels, float* __restrict__ out)
{
    int q = blockIdx.x * 4 + (threadIdx.x >> 6);   // 0..NQ-1
    int c = threadIdx.x & 63;
    float bv = labels[(size_t)(NS + q) * 64 + c];
    int   bi = c;
#pragma unroll
    for (int off = 32; off >= 1; off >>= 1) {
        float ov = __shfl_xor(bv, off, 64);
        int   oi = __shfl_xor(bi, off, 64);
        if (ov > bv || (ov == bv && oi < bi)) { bv = ov; bi = oi; }
    }
    out[(size_t)q * 64 + c] = (c == bi) ? 1.0f : 0.0f;
}

// ---------- launch ----------
extern "C" void kernel_launch(void* const* d_in, const int* in_sizes, int n_in,
                              void* d_out, int out_size, void* d_ws, size_t ws_size,
                              hipStream_t stream)
{
    const float* support = (const float*)d_in[0];
    const float* query   = (const float*)d_in[1];
    const int*   slab    = (const int*)d_in[2];
    const float* W       = (const float*)d_in[3];
    float* out = (float*)d_out;
    char*  ws  = (char*)d_ws;

    // workspace (phase-aliased), total 13,664,256 B:
    //   [0, 4M)      Ghi  -> bits [0,8M) after dist
    //   [4M, 8M)     Glo
    //   [8M, +32K)   sq (live through dist)
    //   [CV_OFF ...) sqpart (embed->sqsum) / cval (dist->merge) / la
    //   [CI_OFF ...) cidx (dist->merge) / lb
    const size_t GHI_OFF = 0;
    const size_t GLO_OFF = 4194304;
    const size_t SQ_OFF  = 8388608;
    const size_t CV_OFF  = 8421376;
    const size_t CI_OFF  = CV_OFF + (size_t)NN * NSPLIT * KNB * 4;   // +2,621,440

    bf16x8*       Ghi  = (bf16x8*)(ws + GHI_OFF);
    bf16x8*       Glo  = (bf16x8*)(ws + GLO_OFF);
    unsigned int* bits = (unsigned int*)(ws + GHI_OFF);   // aliases Ghi/Glo (dead after dist)
    float*        sq   = (float*)(ws + SQ_OFF);
    float*        sqp  = (float*)(ws + CV_OFF);           // aliases cval (dead before dist writes)
    float*        cval = (float*)(ws + CV_OFF);
    int*          cidx = (int*)  (ws + CI_OFF);
    float*        la   = (float*)(ws + CV_OFF);           // aliases cval (dead after merge)
    float*        lb   = (float*)(ws + CI_OFF);           // aliases cidx

    embed_kernel<<<dim3(128, 4), 256, 0, stream>>>(support, query, W, Ghi, Glo, sqp);
    sqsum_kernel<<<NN / 256, 256, 0, stream>>>(sqp, sq);
    dist_topk_kernel<<<dim3(128, NSPLIT), 256, 0, stream>>>(Ghi, Glo, sq, cval, cidx);
    hipMemsetAsync(bits, 0, (size_t)NN * 256 * sizeof(unsigned int), stream);   // Ghi/Glo dead
    merge_adj_kernel<<<NN / 256, 256, 0, stream>>>(cval, cidx, bits);
    labels_init_kernel<<<(NN * 64) / 256, 256, 0, stream>>>(slab, la);          // cval dead
    prop_kernel<<<NN / 4, 256, 0, stream>>>(bits, la, lb);
    prop_kernel<<<NN / 4, 256, 0, stream>>>(bits, lb, la);
    prop_kernel<<<NN / 4, 256, 0, stream>>>(bits, la, lb);
    argmax_kernel<<<NQ / 4, 256, 0, stream>>>(lb, out);
}

// Round 12
// 470.996 us; speedup vs baseline: 2.4849x; 1.0464x over previous
//
#include <hip/hip_runtime.h>
#include <stdint.h>

#define NS   2048
#define NQ   6144
#define NN   8192      // total nodes
#define IND  512
#define DM   256
#define KNB  10
#define NSPLIT 8
#define PCAP 1536      // prop edge-list capacity per node

#define AS1 __attribute__((address_space(1)))
#define AS3 __attribute__((address_space(3)))

typedef short bf16x8 __attribute__((ext_vector_type(8)));
typedef float f32x4  __attribute__((ext_vector_type(4)));
typedef unsigned long long u64;

// exact RNE fp32 -> bf16 (bits); bf16 exp range == fp32, no denormal hazard
__device__ __forceinline__ unsigned short f2bf(float v)
{
    unsigned int u = __float_as_uint(v);
    unsigned int r = (u + 0x7fffu + ((u >> 16) & 1u)) >> 16;
    return (unsigned short)r;
}
__device__ __forceinline__ float bf2f(unsigned short h)
{
    return __uint_as_float(((unsigned int)h) << 16);
}

// lexicographic (value, index) insert into sorted-ascending top-10 registers
__device__ __forceinline__ void topk_insert(float v, int j, float bval[KNB], int bidx[KNB])
{
    bool better = (v < bval[KNB-1]) || (v == bval[KNB-1] && j < bidx[KNB-1]);
    if (better) {
        float cv = v; int ci = j;
#pragma unroll
        for (int q = 0; q < KNB; ++q) {
            bool sw = (cv < bval[q]) || (cv == bval[q] && ci < bidx[q]);
            if (sw) {
                float tv = bval[q]; bval[q] = cv; cv = tv;
                int   ti = bidx[q]; bidx[q] = ci; ci = ti;
            }
        }
    }
}

// branchless 10-deep bubble insert of a u64 key (d2bits<<32 | j) into sorted-asc list
__device__ __forceinline__ void key_insert(u64 key, u64 K[KNB])
{
    u64 cur = key;
#pragma unroll
    for (int s = 0; s < KNB; ++s) {
        u64 lo = (cur < K[s]) ? cur : K[s];
        u64 hi = (cur < K[s]) ? K[s] : cur;
        K[s] = lo; cur = hi;
    }
}

// ---------- 1) embed: E = concat(support,query) @ W (8192x512x256), 64x64 tiles.
// grid 128x4 = 512 blocks = 2/CU. Per-output fp32 FMA order: k ascending.
// Epilogue packs E into MFMA-fragment-ordered bf16 hi/lo arrays, Q-MAJOR:
//   G[c][q][node][j]  (c=k/32, q=(k>>3)&3, j=k&7; 16 B per (c,q,node))
// (q-major makes dist's staged-tile reads 2-way-bank = free; r11's node-major
//  gave 8-way aliasing -> 1.7e7 conflict cycles.)
// Also writes per-row partial squared norms (exact fp32 from acc).
__global__ __launch_bounds__(256) void embed_kernel(
    const float* __restrict__ support, const float* __restrict__ query,
    const float* __restrict__ W, bf16x8* __restrict__ Ghi, bf16x8* __restrict__ Glo,
    float* __restrict__ sqpart)
{
    __shared__ float smem[64 * 68];      // K-loop: A^T 32x68 | B 32x68 ; epilogue: Etile 64x68
    __shared__ float sqred[64 * 17];
    float* smemA = smem;
    float* smemB = smem + 32 * 68;
    const int t  = threadIdx.x;
    const int i0 = blockIdx.x * 64;
    const int n0 = blockIdx.y * 64;
    const int tx = t & 15, ty = t >> 4;

    float acc[4][4];
#pragma unroll
    for (int m = 0; m < 4; ++m)
#pragma unroll
        for (int n = 0; n < 4; ++n) acc[m][n] = 0.f;

    for (int kc = 0; kc < IND; kc += 32) {
        {   // A: rows i0..i0+64 of concat(support,query), cols kc..kc+32, transposed
            int a  = t >> 2;            // 0..63
            int cg = (t & 3) * 8;       // 0,8,16,24
            int g  = i0 + a;
            const float* src = (g < NS) ? (support + (size_t)g * IND)
                                        : (query + (size_t)(g - NS) * IND);
            src += kc + cg;
#pragma unroll
            for (int q = 0; q < 2; ++q) {
                float4 v = *reinterpret_cast<const float4*>(src + q * 4);
                smemA[(cg + q*4 + 0) * 68 + a] = v.x;
                smemA[(cg + q*4 + 1) * 68 + a] = v.y;
                smemA[(cg + q*4 + 2) * 68 + a] = v.z;
                smemA[(cg + q*4 + 3) * 68 + a] = v.w;
            }
        }
        {   // B: W rows kc..kc+32, cols n0..n0+64 (k-major)
            int r  = t >> 3;            // 0..31
            int cg = (t & 7) * 8;       // 0..56
            const float* src = W + (size_t)(kc + r) * DM + n0 + cg;
#pragma unroll
            for (int q = 0; q < 2; ++q) {
                float4 v = *reinterpret_cast<const float4*>(src + q * 4);
                *reinterpret_cast<float4*>(&smemB[r * 68 + cg + q * 4]) = v;
            }
        }
        __syncthreads();
#pragma unroll
        for (int kk = 0; kk < 32; ++kk) {
            float4 a0 = *reinterpret_cast<const float4*>(&smemA[kk * 68 + ty * 4]);
            float4 b0 = *reinterpret_cast<const float4*>(&smemB[kk * 68 + tx * 4]);
            float af[4] = {a0.x, a0.y, a0.z, a0.w};
            float bf[4] = {b0.x, b0.y, b0.z, b0.w};
#pragma unroll
            for (int m = 0; m < 4; ++m)
#pragma unroll
                for (int n = 0; n < 4; ++n)
                    acc[m][n] += af[m] * bf[n];
        }
        __syncthreads();
    }
    // epilogue: partial row norms + stage E tile to LDS (smemA/B dead), pack bf16 hi/lo
#pragma unroll
    for (int m = 0; m < 4; ++m) {
        float s = 0.f;
#pragma unroll
        for (int n = 0; n < 4; ++n) {
            float v = acc[m][n];
            s += v * v;
            smem[(ty * 4 + m) * 68 + tx * 4 + n] = v;
        }
        sqred[(ty * 4 + m) * 17 + tx] = s;
    }
    __syncthreads();
#pragma unroll
    for (int e = 0; e < 2; ++e) {
        int g  = t * 2 + e;              // 0..511 = 64 rows x 2 chunks x 4 quads
        int rl = g >> 3;
        int ch = (g >> 2) & 1;
        int qq = g & 3;
        const float* ep = &smem[rl * 68 + ch * 32 + qq * 8];
        bf16x8 h8, l8;
#pragma unroll
        for (int jj = 0; jj < 8; ++jj) {
            float v = ep[jj];
            unsigned short hu = f2bf(v);
            float hf = bf2f(hu);
            unsigned short lu = f2bf(v - hf);
            h8[jj] = (short)hu;
            l8[jj] = (short)lu;
        }
        int cc = blockIdx.y * 2 + ch;
        size_t gi = ((size_t)(cc * 4 + qq)) * NN + (i0 + rl);   // q-major
        Ghi[gi] = h8;
        Glo[gi] = l8;
    }
    if (t < 64) {
        float s = 0.f;
#pragma unroll
        for (int x = 0; x < 16; ++x) s += sqred[t * 17 + x];
        sqpart[(size_t)blockIdx.y * NN + i0 + t] = s;
    }
}

// ---------- 2) combine the four column-quarter partial norms ----------
__global__ __launch_bounds__(256) void sqsum_kernel(const float* __restrict__ sqpart,
                                                    float* __restrict__ sq)
{
    int i = blockIdx.x * 256 + threadIdx.x;
    sq[i] = ((sqpart[i] + sqpart[NN + i]) + sqpart[2 * NN + i]) + sqpart[3 * NN + i];
}

// ---------- 3) fused distance MFMA-GEMM + streaming per-row top-10 ----------
// r11 learnings applied:
//  * __launch_bounds__(256,2): VGPR cap ~128 (law: ~256/arg; 4->64, 3->84 measured).
//    r11's default pick of 64 VGPR forced K[]/acc into AGPR shuttling -> VALU 65%.
//    LDS (40960 B) caps blocks/CU at 4 regardless, so 4 waves/SIMD is preserved.
//  * q-major G: staged-tile ds_read start bank = 4*lm -> all 8 bank-groups at
//    2-way (free). r11's node-major gave 8-way (1.7e7 conflict cycles).
// Structure otherwise as r11: col tile staged ONCE per block via global_load_lds
// width 16 (double-buffered, 1 barrier/iter); operand-flipped MFMA (lane&15==row);
// per-lane u64-key LDS stacks, predicated push, ballot-bounded drains.
// LDS = 32 KB stage + 8 KB stacks = 40960 B -> 4 blocks/CU. Grid 128x8 = 1024.
__global__ __launch_bounds__(256, 2) void dist_topk_kernel(
    const bf16x8* __restrict__ Ghi, const bf16x8* __restrict__ Glo,
    const float* __restrict__ sq, float* __restrict__ cval, int* __restrict__ cidx)
{
    __shared__ bf16x8 stage[2][1024];            // 2 x 16 KB: [0,512)=hi, [512,1024)=lo; q-major
    __shared__ u64 stk[4][256];                  // 8 KB, slot-major per-thread stacks
    const int t  = threadIdx.x;
    const int l  = t & 63, w = t >> 6;
    const int lm = l & 15, q = l >> 4;
    const int i0 = blockIdx.x * 64;
    const int row = i0 + 16 * w + lm;            // this lane's row
    const int split = blockIdx.y;

    const float  sqi    = sq[row];
    const size_t rowIdx = (size_t)q * NN + row;  // row-frag index within a c-chunk (q-major)

    u64 K[KNB];
#pragma unroll
    for (int s = 0; s < KNB; ++s) K[s] = ~0ull;
    u64 thr = ~0ull;
    int cnt = 0;

    auto drain = [&]() {
        u64 live = __ballot(cnt > 0);
        while (live) {
            if (cnt > 0) {
                --cnt;
                u64 key = stk[cnt][t];
                if (key < thr) {
                    key_insert(key, K);
                    thr = K[KNB - 1];
                }
            }
            live = __ballot(cnt > 0);
        }
    };

    // async-stage the col tile for flattened iteration it (jt=it>>3, c=it&7) into buf b.
    // Tile = 512 frags, q-major (frag f: q=f>>7, col=f&127). Wave w stages frags
    // [256w', 256w'+256) of hi (w<2) or lo (w>=2), w'=w&1; each 64-frag issue lies
    // inside one q-region -> contiguous global source (wave-uniform base + lane*16).
    auto stage_issue = [&](int it, int b) {
        const int jt = split * 8 + (it >> 3);
        const int c  = it & 7;
        const int j0 = jt * 128;
        const size_t cbase = (size_t)c * (NN * 4);
        const bool hi = (w < 2);
        const int  wf = (w & 1) * 256;           // frag offset within hi/lo half
        const bf16x8* gsel = hi ? Ghi : Glo;
#pragma unroll
        for (int u = 0; u < 4; ++u) {
            const int f  = wf + u * 64;
            const int qr = f >> 7, col0 = f & 127;
            const bf16x8* g = gsel + cbase + (size_t)qr * NN + j0 + col0 + l;
            __builtin_amdgcn_global_load_lds((const AS1 void*)g,
                                             (AS3 void*)&stage[b][(hi ? 0 : 512) + f],
                                             16, 0, 0);
        }
    };

    stage_issue(0, 0);
    __syncthreads();                             // drains vmcnt -> stage 0 resident

    f32x4 acc[8];
    for (int it = 0; it < 64; ++it) {
        const int c = it & 7;
        const int b = it & 1;
        if (it + 1 < 64) stage_issue(it + 1, (it + 1) & 1);
        if (c == 0) {
#pragma unroll
            for (int mt = 0; mt < 8; ++mt) acc[mt] = (f32x4){0.f, 0.f, 0.f, 0.f};
        }
        const size_t co = (size_t)c * (NN * 4);
        const bf16x8 Bh = Ghi[co + rowIdx];      // row frags: tiny working set, L1/L2-hit
        const bf16x8 Bl = Glo[co + rowIdx];
        const bf16x8* sh = &stage[b][0];
        const bf16x8* sl = &stage[b][512];
        const int fq = q * 128 + lm;             // q-major frag base for this lane
#pragma unroll
        for (int mt = 0; mt < 8; ++mt) {
            const int fi = fq + 16 * mt;
            const bf16x8 Ah = sh[fi];
            const bf16x8 Al = sl[fi];
            f32x4 a = acc[mt];
            a = __builtin_amdgcn_mfma_f32_16x16x32_bf16(Ah, Bh, a, 0, 0, 0);
            a = __builtin_amdgcn_mfma_f32_16x16x32_bf16(Ah, Bl, a, 0, 0, 0);
            a = __builtin_amdgcn_mfma_f32_16x16x32_bf16(Al, Bh, a, 0, 0, 0);
            a = __builtin_amdgcn_mfma_f32_16x16x32_bf16(Al, Bl, a, 0, 0, 0);
            acc[mt] = a;
        }
        if (c == 7) {
            // per-jt epilogue: d2 from registers; predicated push; drain per mt
            const int j0 = split * 1024 + (it >> 3) * 128;
#pragma unroll
            for (int mt = 0; mt < 8; ++mt) {
                const int jb = j0 + 16 * mt + 4 * q;
                const f32x4 sqj = *reinterpret_cast<const f32x4*>(&sq[jb]);
#pragma unroll
                for (int r = 0; r < 4; ++r) {
                    float d2 = fmaxf(sqi + sqj[r] - 2.0f * acc[mt][r], 0.0f);
                    u64 key = ((u64)__float_as_uint(d2) << 32) | (unsigned)(jb + r);
                    if (key < thr) { stk[cnt][t] = key; ++cnt; }   // cnt <= 3 (depth 4)
                }
                drain();                          // empties stack; cheap when empty
            }
        }
        __syncthreads();   // consumers done with buf b; stage of it+1 drained (vmcnt)
    }
    // cross-q merge (4 lanes of a wave share a row). Dump region reuses the stage
    // buffers (all compute finished at the loop's final barrier). Same-wave
    // write->read needs only lgkmcnt (compiler-inserted).
    u64* dump = reinterpret_cast<u64*>(&stage[0][0]);    // 256*10*8 B = 20480 <= 32768
#pragma unroll
    for (int s = 0; s < KNB; ++s) dump[t * KNB + s] = K[s];
    if (q == 0) {
#pragma unroll
        for (int qq = 1; qq < 4; ++qq)
#pragma unroll
            for (int s = 0; s < KNB; ++s) {
                u64 key = dump[(t + qq * 16) * KNB + s];
                if (key < thr) {
                    key_insert(key, K);
                    thr = K[KNB - 1];
                }
            }
        size_t base = (size_t)row * (NSPLIT * KNB) + split * KNB;
#pragma unroll
        for (int s = 0; s < KNB; ++s) {
            cval[base + s] = __uint_as_float((unsigned)(K[s] >> 32));
            cidx[base + s] = (int)(K[s] & 0xFFFFFFFFu);
        }
    }
}

// ---------- 4) merge partial top-10s -> global top-10, build symmetric adjacency bitset ----------
__global__ __launch_bounds__(256) void merge_adj_kernel(
    const float* __restrict__ cval, const int* __restrict__ cidx,
    unsigned int* __restrict__ bits)
{
    int i = blockIdx.x * blockDim.x + threadIdx.x;
    if (i >= NN) return;
    float bval[KNB]; int bidx[KNB];
#pragma unroll
    for (int s = 0; s < KNB; ++s) { bval[s] = 3.0e38f; bidx[s] = 0x7fffffff; }
    for (int s = 0; s < NSPLIT * KNB; ++s) {
        float v = cval[(size_t)i * (NSPLIT * KNB) + s];
        int   j = cidx[(size_t)i * (NSPLIT * KNB) + s];
        topk_insert(v, j, bval, bidx);
    }
#pragma unroll
    for (int s = 0; s < KNB; ++s) {
        int j = bidx[s];
        atomicOr(&bits[(size_t)i * 256 + (j >> 5)], 1u << (j & 31));
        atomicOr(&bits[(size_t)j * 256 + (i >> 5)], 1u << (i & 31));
    }
}

// ---------- 5) label init ----------
__global__ __launch_bounds__(256) void labels_init_kernel(const int* __restrict__ slab, float* __restrict__ la)
{
    int tid = blockIdx.x * blockDim.x + threadIdx.x;   // NN*64 threads
    int i = tid >> 6, c = tid & 63;
    float v = 0.f;
    if (i < NS) v = (slab[i] == c) ? 1.f : 0.f;
    la[tid] = v;
}

// ---------- 6) one propagation step: lout[i] = sum_j (1/deg_i)*lin[j] over N(i), j ascending.
__global__ __launch_bounds__(256) void prop_kernel(
    const unsigned int* __restrict__ bits, const float* __restrict__ lin, float* __restrict__ lout)
{
    __shared__ int lists[4][PCAP];
    const int grp = threadIdx.x >> 6;
    const int c   = threadIdx.x & 63;
    const int i   = blockIdx.x * 4 + grp;
    const unsigned int* row = bits + (size_t)i * 256;

    unsigned int mw[4];
#pragma unroll
    for (int k = 0; k < 4; ++k) mw[k] = row[4 * c + k];
    int cnt = __popc(mw[0]) + __popc(mw[1]) + __popc(mw[2]) + __popc(mw[3]);
    int incl = cnt;
#pragma unroll
    for (int d = 1; d < 64; d <<= 1) {
        int nb = __shfl_up(incl, d, 64);
        if (c >= d) incl += nb;
    }
    const int off = incl - cnt;
    const int deg = __shfl(incl, 63, 64);
    const bool use_list = (deg <= PCAP);

    if (use_list) {
        int p = off;
#pragma unroll
        for (int k = 0; k < 4; ++k) {
            unsigned int m = mw[k];
            while (m) {
                int b = __ffs(m) - 1;
                m &= m - 1;
                lists[grp][p++] = (4 * c + k) * 32 + b;
            }
        }
    }
    __syncthreads();

    const float tinv = 1.0f / (float)deg;          // deg >= 1 (self-loop)
    float acc = 0.f;
    if (use_list) {
        const int* lst = lists[grp];
        int d = 0;
        for (; d + 4 <= deg; d += 4) {
            int j0 = lst[d], j1 = lst[d + 1], j2 = lst[d + 2], j3 = lst[d + 3];
            float x0 = lin[(size_t)j0 * 64 + c];
            float x1 = lin[(size_t)j1 * 64 + c];
            float x2 = lin[(size_t)j2 * 64 + c];
            float x3 = lin[(size_t)j3 * 64 + c];
            acc += __fmul_rn(tinv, x0);
            acc += __fmul_rn(tinv, x1);
            acc += __fmul_rn(tinv, x2);
            acc += __fmul_rn(tinv, x3);
        }
        for (; d < deg; ++d) {
            int j = lst[d];
            acc += __fmul_rn(tinv, lin[(size_t)j * 64 + c]);
        }
    } else {
        for (int w2 = 0; w2 < 256; ++w2) {
            unsigned int m = row[w2];
            while (m) {
                int b = __ffs(m) - 1;
                m &= m - 1;
                int j = w2 * 32 + b;
                acc += __fmul_rn(tinv, lin[(size_t)j * 64 + c]);
            }
        }
    }
    lout[(size_t)i * 64 + c] = acc;
}

// ---------- 7) argmax (first-index tie-break) -> one-hot ----------
__global__ __launch_bounds__(256) void argmax_kernel(const float* __restrict__ labels, float* __restrict__ out)
{
    int q = blockIdx.x * 4 + (threadIdx.x >> 6);   // 0..NQ-1
    int c = threadIdx.x & 63;
    float bv = labels[(size_t)(NS + q) * 64 + c];
    int   bi = c;
#pragma unroll
    for (int off = 32; off >= 1; off >>= 1) {
        float ov = __shfl_xor(bv, off, 64);
        int   oi = __shfl_xor(bi, off, 64);
        if (ov > bv || (ov == bv && oi < bi)) { bv = ov; bi = oi; }
    }
    out[(size_t)q * 64 + c] = (c == bi) ? 1.0f : 0.0f;
}

// ---------- launch ----------
extern "C" void kernel_launch(void* const* d_in, const int* in_sizes, int n_in,
                              void* d_out, int out_size, void* d_ws, size_t ws_size,
                              hipStream_t stream)
{
    const float* support = (const float*)d_in[0];
    const float* query   = (const float*)d_in[1];
    const int*   slab    = (const int*)d_in[2];
    const float* W       = (const float*)d_in[3];
    float* out = (float*)d_out;
    char*  ws  = (char*)d_ws;

    // workspace (phase-aliased), total 13,664,256 B:
    //   [0, 4M)      Ghi  -> bits [0,8M) after dist
    //   [4M, 8M)     Glo
    //   [8M, +32K)   sq (live through dist)
    //   [CV_OFF ...) sqpart (embed->sqsum) / cval (dist->merge) / la
    //   [CI_OFF ...) cidx (dist->merge) / lb
    const size_t GHI_OFF = 0;
    const size_t GLO_OFF = 4194304;
    const size_t SQ_OFF  = 8388608;
    const size_t CV_OFF  = 8421376;
    const size_t CI_OFF  = CV_OFF + (size_t)NN * NSPLIT * KNB * 4;   // +2,621,440

    bf16x8*       Ghi  = (bf16x8*)(ws + GHI_OFF);
    bf16x8*       Glo  = (bf16x8*)(ws + GLO_OFF);
    unsigned int* bits = (unsigned int*)(ws + GHI_OFF);   // aliases Ghi/Glo (dead after dist)
    float*        sq   = (float*)(ws + SQ_OFF);
    float*        sqp  = (float*)(ws + CV_OFF);           // aliases cval (dead before dist writes)
    float*        cval = (float*)(ws + CV_OFF);
    int*          cidx = (int*)  (ws + CI_OFF);
    float*        la   = (float*)(ws + CV_OFF);           // aliases cval (dead after merge)
    float*        lb   = (float*)(ws + CI_OFF);           // aliases cidx

    embed_kernel<<<dim3(128, 4), 256, 0, stream>>>(support, query, W, Ghi, Glo, sqp);
    sqsum_kernel<<<NN / 256, 256, 0, stream>>>(sqp, sq);
    dist_topk_kernel<<<dim3(128, NSPLIT), 256, 0, stream>>>(Ghi, Glo, sq, cval, cidx);
    hipMemsetAsync(bits, 0, (size_t)NN * 256 * sizeof(unsigned int), stream);   // Ghi/Glo dead
    merge_adj_kernel<<<NN / 256, 256, 0, stream>>>(cval, cidx, bits);
    labels_init_kernel<<<(NN * 64) / 256, 256, 0, stream>>>(slab, la);          // cval dead
    prop_kernel<<<NN / 4, 256, 0, stream>>>(bits, la, lb);
    prop_kernel<<<NN / 4, 256, 0, stream>>>(bits, lb, la);
    prop_kernel<<<NN / 4, 256, 0, stream>>>(bits, la, lb);
    argmax_kernel<<<NQ / 4, 256, 0, stream>>>(lb, out);
}

// Round 13
// 462.840 us; speedup vs baseline: 2.5287x; 1.0176x over previous
//
#include <hip/hip_runtime.h>
#include <stdint.h>

#define NS   2048
#define NQ   6144
#define NN   8192      // total nodes
#define IND  512
#define DM   256
#define KNB  10
#define NSPLIT 8
#define PCAP 1536      // prop edge-list capacity per node

#define AS1 __attribute__((address_space(1)))
#define AS3 __attribute__((address_space(3)))

typedef short bf16x8 __attribute__((ext_vector_type(8)));
typedef float f32x4  __attribute__((ext_vector_type(4)));
typedef unsigned long long u64;

// exact RNE fp32 -> bf16 (bits); bf16 exp range == fp32, no denormal hazard
__device__ __forceinline__ unsigned short f2bf(float v)
{
    unsigned int u = __float_as_uint(v);
    unsigned int r = (u + 0x7fffu + ((u >> 16) & 1u)) >> 16;
    return (unsigned short)r;
}
__device__ __forceinline__ float bf2f(unsigned short h)
{
    return __uint_as_float(((unsigned int)h) << 16);
}

// lexicographic (value, index) insert into sorted-ascending top-10 registers
__device__ __forceinline__ void topk_insert(float v, int j, float bval[KNB], int bidx[KNB])
{
    bool better = (v < bval[KNB-1]) || (v == bval[KNB-1] && j < bidx[KNB-1]);
    if (better) {
        float cv = v; int ci = j;
#pragma unroll
        for (int q = 0; q < KNB; ++q) {
            bool sw = (cv < bval[q]) || (cv == bval[q] && ci < bidx[q]);
            if (sw) {
                float tv = bval[q]; bval[q] = cv; cv = tv;
                int   ti = bidx[q]; bidx[q] = ci; ci = ti;
            }
        }
    }
}

// branchless 10-deep bubble insert of a u64 key (d2bits<<32 | j) into sorted-asc list
__device__ __forceinline__ void key_insert(u64 key, u64 K[KNB])
{
    u64 cur = key;
#pragma unroll
    for (int s = 0; s < KNB; ++s) {
        u64 lo = (cur < K[s]) ? cur : K[s];
        u64 hi = (cur < K[s]) ? K[s] : cur;
        K[s] = lo; cur = hi;
    }
}

// ---------- 0) pack W into transposed bf16 hi/lo MFMA fragments ----------
// Wt frag f = c<<10 | q<<8 | dim : 8 bf16 of W[32c+8q+j][dim], j=0..7.
// 16384 frags x 16 B x 2 = 512 KB (L2-resident during embed).
__global__ __launch_bounds__(256) void wpack_kernel(const float* __restrict__ W,
                                                    bf16x8* __restrict__ Wthi,
                                                    bf16x8* __restrict__ Wtlo)
{
    int f = blockIdx.x * 256 + threadIdx.x;       // 0..16383
    int dim = f & 255, qp = (f >> 8) & 3, c = f >> 10;
    int k0 = 32 * c + 8 * qp;
    bf16x8 h8, l8;
#pragma unroll
    for (int j = 0; j < 8; ++j) {
        float v = W[(size_t)(k0 + j) * DM + dim];
        unsigned short hu = f2bf(v);
        float hf = bf2f(hu);
        unsigned short lu = f2bf(v - hf);
        h8[j] = (short)hu; l8[j] = (short)lu;
    }
    Wthi[f] = h8; Wtlo[f] = l8;
}

// ---------- 1) embed via bf16-split MFMA: E = concat(support,query) @ W ----------
// Block = 16 nodes x 256 dims (all of DM), 4 waves (wave w: dims 64w..64w+63).
// grid 512 = 2/CU. Phases (3 barriers total):
//  conv: inputs -> bf16 hi/lo node-frags in LDS, frag-ordered (cq*16+node) ->
//        every ds access is exactly 8 dwords/bank (conflict-free minimum).
//  K-loop (no barriers): 16 c-chunks x 4 nt x 4 MFMA products; A=node frags (m),
//        B=Wt frags (n=dim) -> D rows = node (quad*4+r), cols = dim (lane&15).
//  epilogue: acc -> LDS E-tile [16][260] (stride 260: 2-way banks, 16B-aligned
//        rows) -> pack G q-major (as r12) + write sq DIRECTLY (sqsum kernel gone).
// Numerics: E = MFMA(hi+lo split), ~1e-5 relative error — same class as the
// validated distance split (r5-r12 absmax 0); G and sq derive consistently from
// the same acc, so downstream d2 is self-consistent.
__global__ __launch_bounds__(256) void embed_kernel(
    const float* __restrict__ support, const float* __restrict__ query,
    const bf16x8* __restrict__ Wthi, const bf16x8* __restrict__ Wtlo,
    bf16x8* __restrict__ Ghi, bf16x8* __restrict__ Glo, float* __restrict__ sq)
{
    __shared__ __align__(16) char lds[36928];
    bf16x8* Ehf = reinterpret_cast<bf16x8*>(lds);            // [1024] node frags (hi)
    bf16x8* Elf = Ehf + 1024;                                // [1024] (lo)
    float*  et  = reinterpret_cast<float*>(lds);             // epilogue alias: [16][260]
    float*  sqred = reinterpret_cast<float*>(lds + 32768);   // [16][65]
    const int t = threadIdx.x;
    const int l = t & 63, w = t >> 6;
    const int lm = l & 15, q = l >> 4;
    const int i0 = blockIdx.x * 16;

    // conv: each thread packs 4 frags (node = t&15, cq = t>>4 + 16i; k0 = 8*cq)
    {
        const int node = t & 15;
        const int g = i0 + node;
        const float* src = (g < NS) ? (support + (size_t)g * IND)
                                    : (query + (size_t)(g - NS) * IND);
#pragma unroll
        for (int i = 0; i < 4; ++i) {
            int cq = (t >> 4) + 16 * i;
            const float* p = src + cq * 8;
            float4 v0 = *reinterpret_cast<const float4*>(p);
            float4 v1 = *reinterpret_cast<const float4*>(p + 4);
            float vv[8] = {v0.x, v0.y, v0.z, v0.w, v1.x, v1.y, v1.z, v1.w};
            bf16x8 h8, l8;
#pragma unroll
            for (int j = 0; j < 8; ++j) {
                unsigned short hu = f2bf(vv[j]);
                float hf = bf2f(hu);
                unsigned short lu = f2bf(vv[j] - hf);
                h8[j] = (short)hu; l8[j] = (short)lu;
            }
            Ehf[cq * 16 + node] = h8;
            Elf[cq * 16 + node] = l8;
        }
    }
    __syncthreads();

    f32x4 acc[4];
#pragma unroll
    for (int nt = 0; nt < 4; ++nt) acc[nt] = (f32x4){0.f, 0.f, 0.f, 0.f};
    const int dimb = 64 * w + lm;
    for (int c = 0; c < 16; ++c) {
        const bf16x8 Anh = Ehf[(c * 4 + q) * 16 + lm];
        const bf16x8 Anl = Elf[(c * 4 + q) * 16 + lm];
        const int fb = c * 1024 + q * 256 + dimb;
#pragma unroll
        for (int nt = 0; nt < 4; ++nt) {
            const bf16x8 Wh = Wthi[fb + 16 * nt];
            const bf16x8 Wl = Wtlo[fb + 16 * nt];
            f32x4 a = acc[nt];
            a = __builtin_amdgcn_mfma_f32_16x16x32_bf16(Anh, Wh, a, 0, 0, 0);
            a = __builtin_amdgcn_mfma_f32_16x16x32_bf16(Anh, Wl, a, 0, 0, 0);
            a = __builtin_amdgcn_mfma_f32_16x16x32_bf16(Anl, Wh, a, 0, 0, 0);
            a = __builtin_amdgcn_mfma_f32_16x16x32_bf16(Anl, Wl, a, 0, 0, 0);
            acc[nt] = a;
        }
    }
    __syncthreads();                             // Ehf/Elf dead -> reuse as E-tile

    // store E tile + per-lane sq partials (lane's node for reg r: 4q+r)
#pragma unroll
    for (int r = 0; r < 4; ++r) {
        float s = 0.f;
#pragma unroll
        for (int nt = 0; nt < 4; ++nt) {
            float v = acc[nt][r];
            et[(4 * q + r) * 260 + dimb + 16 * nt] = v;
            s += v * v;
        }
        sqred[(4 * q + r) * 65 + w * 16 + lm] = s;
    }
    __syncthreads();

    // pack G (q-major, as r12) + finalize sq
#pragma unroll
    for (int i = 0; i < 2; ++i) {
        int f = t + 256 * i;                     // 0..511 = 8 cd x 4 qd x 16 nodes
        int node = f & 15, qd = (f >> 4) & 3, cd = f >> 6;
        const float* ep = &et[node * 260 + 32 * cd + 8 * qd];
        bf16x8 h8, l8;
#pragma unroll
        for (int j = 0; j < 8; ++j) {
            float v = ep[j];
            unsigned short hu = f2bf(v);
            float hf = bf2f(hu);
            unsigned short lu = f2bf(v - hf);
            h8[j] = (short)hu; l8[j] = (short)lu;
        }
        size_t gi = (size_t)(cd * 4 + qd) * NN + i0 + node;
        Ghi[gi] = h8;
        Glo[gi] = l8;
    }
    if (t < 16) {
        float s = 0.f;
#pragma unroll
        for (int x = 0; x < 64; ++x) s += sqred[t * 65 + x];
        sq[i0 + t] = s;
    }
}

// ---------- 3) fused distance MFMA-GEMM + streaming per-row top-10 ----------
// UNCHANGED from r12 (for attribution): q-major staged col tile via
// global_load_lds width 16, double-buffered, 1 barrier/iter; operand-flipped
// MFMA (lane&15==row); per-lane u64-key LDS stacks, predicated push,
// ballot-bounded drains. LDS 40960 B -> 4 blocks/CU. Grid 128x8 = 1024.
__global__ __launch_bounds__(256, 2) void dist_topk_kernel(
    const bf16x8* __restrict__ Ghi, const bf16x8* __restrict__ Glo,
    const float* __restrict__ sq, float* __restrict__ cval, int* __restrict__ cidx)
{
    __shared__ bf16x8 stage[2][1024];            // 2 x 16 KB: [0,512)=hi, [512,1024)=lo; q-major
    __shared__ u64 stk[4][256];                  // 8 KB, slot-major per-thread stacks
    const int t  = threadIdx.x;
    const int l  = t & 63, w = t >> 6;
    const int lm = l & 15, q = l >> 4;
    const int i0 = blockIdx.x * 64;
    const int row = i0 + 16 * w + lm;            // this lane's row
    const int split = blockIdx.y;

    const float  sqi    = sq[row];
    const size_t rowIdx = (size_t)q * NN + row;  // row-frag index within a c-chunk (q-major)

    u64 K[KNB];
#pragma unroll
    for (int s = 0; s < KNB; ++s) K[s] = ~0ull;
    u64 thr = ~0ull;
    int cnt = 0;

    auto drain = [&]() {
        u64 live = __ballot(cnt > 0);
        while (live) {
            if (cnt > 0) {
                --cnt;
                u64 key = stk[cnt][t];
                if (key < thr) {
                    key_insert(key, K);
                    thr = K[KNB - 1];
                }
            }
            live = __ballot(cnt > 0);
        }
    };

    auto stage_issue = [&](int it, int b) {
        const int jt = split * 8 + (it >> 3);
        const int c  = it & 7;
        const int j0 = jt * 128;
        const size_t cbase = (size_t)c * (NN * 4);
        const bool hi = (w < 2);
        const int  wf = (w & 1) * 256;           // frag offset within hi/lo half
        const bf16x8* gsel = hi ? Ghi : Glo;
#pragma unroll
        for (int u = 0; u < 4; ++u) {
            const int f  = wf + u * 64;
            const int qr = f >> 7, col0 = f & 127;
            const bf16x8* g = gsel + cbase + (size_t)qr * NN + j0 + col0 + l;
            __builtin_amdgcn_global_load_lds((const AS1 void*)g,
                                             (AS3 void*)&stage[b][(hi ? 0 : 512) + f],
                                             16, 0, 0);
        }
    };

    stage_issue(0, 0);
    __syncthreads();                             // drains vmcnt -> stage 0 resident

    f32x4 acc[8];
    for (int it = 0; it < 64; ++it) {
        const int c = it & 7;
        const int b = it & 1;
        if (it + 1 < 64) stage_issue(it + 1, (it + 1) & 1);
        if (c == 0) {
#pragma unroll
            for (int mt = 0; mt < 8; ++mt) acc[mt] = (f32x4){0.f, 0.f, 0.f, 0.f};
        }
        const size_t co = (size_t)c * (NN * 4);
        const bf16x8 Bh = Ghi[co + rowIdx];      // row frags: tiny working set, L1/L2-hit
        const bf16x8 Bl = Glo[co + rowIdx];
        const bf16x8* sh = &stage[b][0];
        const bf16x8* sl = &stage[b][512];
        const int fq = q * 128 + lm;             // q-major frag base for this lane
#pragma unroll
        for (int mt = 0; mt < 8; ++mt) {
            const int fi = fq + 16 * mt;
            const bf16x8 Ah = sh[fi];
            const bf16x8 Al = sl[fi];
            f32x4 a = acc[mt];
            a = __builtin_amdgcn_mfma_f32_16x16x32_bf16(Ah, Bh, a, 0, 0, 0);
            a = __builtin_amdgcn_mfma_f32_16x16x32_bf16(Ah, Bl, a, 0, 0, 0);
            a = __builtin_amdgcn_mfma_f32_16x16x32_bf16(Al, Bh, a, 0, 0, 0);
            a = __builtin_amdgcn_mfma_f32_16x16x32_bf16(Al, Bl, a, 0, 0, 0);
            acc[mt] = a;
        }
        if (c == 7) {
            const int j0 = split * 1024 + (it >> 3) * 128;
#pragma unroll
            for (int mt = 0; mt < 8; ++mt) {
                const int jb = j0 + 16 * mt + 4 * q;
                const f32x4 sqj = *reinterpret_cast<const f32x4*>(&sq[jb]);
#pragma unroll
                for (int r = 0; r < 4; ++r) {
                    float d2 = fmaxf(sqi + sqj[r] - 2.0f * acc[mt][r], 0.0f);
                    u64 key = ((u64)__float_as_uint(d2) << 32) | (unsigned)(jb + r);
                    if (key < thr) { stk[cnt][t] = key; ++cnt; }   // cnt <= 3 (depth 4)
                }
                drain();
            }
        }
        __syncthreads();   // consumers done with buf b; stage of it+1 drained (vmcnt)
    }
    // cross-q merge: dump region aliases other waves' stacks -> barrier first (r9 bug)
    __syncthreads();
    u64* dump = reinterpret_cast<u64*>(&stage[0][0]);    // 256*10*8 B = 20480 <= 32768
#pragma unroll
    for (int s = 0; s < KNB; ++s) dump[t * KNB + s] = K[s];
    if (q == 0) {
#pragma unroll
        for (int qq = 1; qq < 4; ++qq)
#pragma unroll
            for (int s = 0; s < KNB; ++s) {
                u64 key = dump[(t + qq * 16) * KNB + s];
                if (key < thr) {
                    key_insert(key, K);
                    thr = K[KNB - 1];
                }
            }
        size_t base = (size_t)row * (NSPLIT * KNB) + split * KNB;
#pragma unroll
        for (int s = 0; s < KNB; ++s) {
            cval[base + s] = __uint_as_float((unsigned)(K[s] >> 32));
            cidx[base + s] = (int)(K[s] & 0xFFFFFFFFu);
        }
    }
}

// ---------- 4) merge partial top-10s -> global top-10, build symmetric adjacency bitset ----------
__global__ __launch_bounds__(256) void merge_adj_kernel(
    const float* __restrict__ cval, const int* __restrict__ cidx,
    unsigned int* __restrict__ bits)
{
    int i = blockIdx.x * blockDim.x + threadIdx.x;
    if (i >= NN) return;
    float bval[KNB]; int bidx[KNB];
#pragma unroll
    for (int s = 0; s < KNB; ++s) { bval[s] = 3.0e38f; bidx[s] = 0x7fffffff; }
    for (int s = 0; s < NSPLIT * KNB; ++s) {
        float v = cval[(size_t)i * (NSPLIT * KNB) + s];
        int   j = cidx[(size_t)i * (NSPLIT * KNB) + s];
        topk_insert(v, j, bval, bidx);
    }
#pragma unroll
    for (int s = 0; s < KNB; ++s) {
        int j = bidx[s];
        atomicOr(&bits[(size_t)i * 256 + (j >> 5)], 1u << (j & 31));
        atomicOr(&bits[(size_t)j * 256 + (i >> 5)], 1u << (i & 31));
    }
}

// ---------- 5) label init ----------
__global__ __launch_bounds__(256) void labels_init_kernel(const int* __restrict__ slab, float* __restrict__ la)
{
    int tid = blockIdx.x * blockDim.x + threadIdx.x;   // NN*64 threads
    int i = tid >> 6, c = tid & 63;
    float v = 0.f;
    if (i < NS) v = (slab[i] == c) ? 1.f : 0.f;
    la[tid] = v;
}

// ---------- 6) one propagation step: lout[i] = sum_j (1/deg_i)*lin[j] over N(i), j ascending.
__global__ __launch_bounds__(256) void prop_kernel(
    const unsigned int* __restrict__ bits, const float* __restrict__ lin, float* __restrict__ lout)
{
    __shared__ int lists[4][PCAP];
    const int grp = threadIdx.x >> 6;
    const int c   = threadIdx.x & 63;
    const int i   = blockIdx.x * 4 + grp;
    const unsigned int* row = bits + (size_t)i * 256;

    unsigned int mw[4];
#pragma unroll
    for (int k = 0; k < 4; ++k) mw[k] = row[4 * c + k];
    int cnt = __popc(mw[0]) + __popc(mw[1]) + __popc(mw[2]) + __popc(mw[3]);
    int incl = cnt;
#pragma unroll
    for (int d = 1; d < 64; d <<= 1) {
        int nb = __shfl_up(incl, d, 64);
        if (c >= d) incl += nb;
    }
    const int off = incl - cnt;
    const int deg = __shfl(incl, 63, 64);
    const bool use_list = (deg <= PCAP);

    if (use_list) {
        int p = off;
#pragma unroll
        for (int k = 0; k < 4; ++k) {
            unsigned int m = mw[k];
            while (m) {
                int b = __ffs(m) - 1;
                m &= m - 1;
                lists[grp][p++] = (4 * c + k) * 32 + b;
            }
        }
    }
    __syncthreads();

    const float tinv = 1.0f / (float)deg;          // deg >= 1 (self-loop)
    float acc = 0.f;
    if (use_list) {
        const int* lst = lists[grp];
        int d = 0;
        for (; d + 4 <= deg; d += 4) {
            int j0 = lst[d], j1 = lst[d + 1], j2 = lst[d + 2], j3 = lst[d + 3];
            float x0 = lin[(size_t)j0 * 64 + c];
            float x1 = lin[(size_t)j1 * 64 + c];
            float x2 = lin[(size_t)j2 * 64 + c];
            float x3 = lin[(size_t)j3 * 64 + c];
            acc += __fmul_rn(tinv, x0);
            acc += __fmul_rn(tinv, x1);
            acc += __fmul_rn(tinv, x2);
            acc += __fmul_rn(tinv, x3);
        }
        for (; d < deg; ++d) {
            int j = lst[d];
            acc += __fmul_rn(tinv, lin[(size_t)j * 64 + c]);
        }
    } else {
        for (int w2 = 0; w2 < 256; ++w2) {
            unsigned int m = row[w2];
            while (m) {
                int b = __ffs(m) - 1;
                m &= m - 1;
                int j = w2 * 32 + b;
                acc += __fmul_rn(tinv, lin[(size_t)j * 64 + c]);
            }
        }
    }
    lout[(size_t)i * 64 + c] = acc;
}

// ---------- 7) argmax (first-index tie-break) -> one-hot ----------
__global__ __launch_bounds__(256) void argmax_kernel(const float* __restrict__ labels, float* __restrict__ out)
{
    int q = blockIdx.x * 4 + (threadIdx.x >> 6);   // 0..NQ-1
    int c = threadIdx.x & 63;
    float bv = labels[(size_t)(NS + q) * 64 + c];
    int   bi = c;
#pragma unroll
    for (int off = 32; off >= 1; off >>= 1) {
        float ov = __shfl_xor(bv, off, 64);
        int   oi = __shfl_xor(bi, off, 64);
        if (ov > bv || (ov == bv && oi < bi)) { bv = ov; bi = oi; }
    }
    out[(size_t)q * 64 + c] = (c == bi) ? 1.0f : 0.0f;
}

// ---------- launch ----------
extern "C" void kernel_launch(void* const* d_in, const int* in_sizes, int n_in,
                              void* d_out, int out_size, void* d_ws, size_t ws_size,
                              hipStream_t stream)
{
    const float* support = (const float*)d_in[0];
    const float* query   = (const float*)d_in[1];
    const int*   slab    = (const int*)d_in[2];
    const float* W       = (const float*)d_in[3];
    float* out = (float*)d_out;
    char*  ws  = (char*)d_ws;

    // workspace (phase-aliased), total 13,664,256 B:
    //   [0, 4M)      Ghi  -> bits [0,8M) after dist
    //   [4M, 8M)     Glo
    //   [8M, +32K)   sq (live through dist)
    //   [CV_OFF ...) Wthi/Wtlo (wpack->embed, 512 KB) / cval (dist->merge) / la
    //   [CI_OFF ...) cidx (dist->merge) / lb
    const size_t GHI_OFF = 0;
    const size_t GLO_OFF = 4194304;
    const size_t SQ_OFF  = 8388608;
    const size_t CV_OFF  = 8421376;
    const size_t CI_OFF  = CV_OFF + (size_t)NN * NSPLIT * KNB * 4;   // +2,621,440

    bf16x8*       Ghi  = (bf16x8*)(ws + GHI_OFF);
    bf16x8*       Glo  = (bf16x8*)(ws + GLO_OFF);
    unsigned int* bits = (unsigned int*)(ws + GHI_OFF);   // aliases Ghi/Glo (dead after dist)
    float*        sq   = (float*)(ws + SQ_OFF);
    bf16x8*       Wthi = (bf16x8*)(ws + CV_OFF);          // aliases cval (dead before dist writes)
    bf16x8*       Wtlo = (bf16x8*)(ws + CV_OFF + 262144);
    float*        cval = (float*)(ws + CV_OFF);
    int*          cidx = (int*)  (ws + CI_OFF);
    float*        la   = (float*)(ws + CV_OFF);           // aliases cval (dead after merge)
    float*        lb   = (float*)(ws + CI_OFF);           // aliases cidx

    wpack_kernel<<<64, 256, 0, stream>>>(W, Wthi, Wtlo);
    embed_kernel<<<512, 256, 0, stream>>>(support, query, Wthi, Wtlo, Ghi, Glo, sq);
    dist_topk_kernel<<<dim3(128, NSPLIT), 256, 0, stream>>>(Ghi, Glo, sq, cval, cidx);
    hipMemsetAsync(bits, 0, (size_t)NN * 256 * sizeof(unsigned int), stream);   // Ghi/Glo dead
    merge_adj_kernel<<<NN / 256, 256, 0, stream>>>(cval, cidx, bits);
    labels_init_kernel<<<(NN * 64) / 256, 256, 0, stream>>>(slab, la);          // cval dead
    prop_kernel<<<NN / 4, 256, 0, stream>>>(bits, la, lb);
    prop_kernel<<<NN / 4, 256, 0, stream>>>(bits, lb, la);
    prop_kernel<<<NN / 4, 256, 0, stream>>>(bits, la, lb);
    argmax_kernel<<<NQ / 4, 256, 0, stream>>>(lb, out);
}

// Round 14
// 453.629 us; speedup vs baseline: 2.5800x; 1.0203x over previous
//
#include <hip/hip_runtime.h>
#include <stdint.h>

#define NS   2048
#define NQ   6144
#define NN   8192      // total nodes
#define IND  512
#define DM   256
#define KNB  10
#define NSPLIT 8
#define PCAP 1536      // prop edge-list capacity per node

#define AS1 __attribute__((address_space(1)))
#define AS3 __attribute__((address_space(3)))

typedef short bf16x8 __attribute__((ext_vector_type(8)));
typedef float f32x4  __attribute__((ext_vector_type(4)));
typedef unsigned long long u64;

// exact RNE fp32 -> bf16 (bits); bf16 exp range == fp32, no denormal hazard
__device__ __forceinline__ unsigned short f2bf(float v)
{
    unsigned int u = __float_as_uint(v);
    unsigned int r = (u + 0x7fffu + ((u >> 16) & 1u)) >> 16;
    return (unsigned short)r;
}
__device__ __forceinline__ float bf2f(unsigned short h)
{
    return __uint_as_float(((unsigned int)h) << 16);
}

// branchless 10-deep bubble insert of a u64 key (d2bits<<32 | j) into sorted-asc list
__device__ __forceinline__ void key_insert(u64 key, u64 K[KNB])
{
    u64 cur = key;
#pragma unroll
    for (int s = 0; s < KNB; ++s) {
        u64 lo = (cur < K[s]) ? cur : K[s];
        u64 hi = (cur < K[s]) ? K[s] : cur;
        K[s] = lo; cur = hi;
    }
}

// ---------- 0) pack W into transposed bf16 hi/lo MFMA fragments ----------
__global__ __launch_bounds__(256) void wpack_kernel(const float* __restrict__ W,
                                                    bf16x8* __restrict__ Wthi,
                                                    bf16x8* __restrict__ Wtlo)
{
    int f = blockIdx.x * 256 + threadIdx.x;       // 0..16383
    int dim = f & 255, qp = (f >> 8) & 3, c = f >> 10;
    int k0 = 32 * c + 8 * qp;
    bf16x8 h8, l8;
#pragma unroll
    for (int j = 0; j < 8; ++j) {
        float v = W[(size_t)(k0 + j) * DM + dim];
        unsigned short hu = f2bf(v);
        float hf = bf2f(hu);
        unsigned short lu = f2bf(v - hf);
        h8[j] = (short)hu; l8[j] = (short)lu;
    }
    Wthi[f] = h8; Wtlo[f] = l8;
}

// ---------- 1) embed via bf16-split MFMA (r13, validated absmax 0) ----------
__global__ __launch_bounds__(256) void embed_kernel(
    const float* __restrict__ support, const float* __restrict__ query,
    const bf16x8* __restrict__ Wthi, const bf16x8* __restrict__ Wtlo,
    bf16x8* __restrict__ Ghi, bf16x8* __restrict__ Glo, float* __restrict__ sq)
{
    __shared__ __align__(16) char lds[36928];
    bf16x8* Ehf = reinterpret_cast<bf16x8*>(lds);            // [1024] node frags (hi)
    bf16x8* Elf = Ehf + 1024;                                // [1024] (lo)
    float*  et  = reinterpret_cast<float*>(lds);             // epilogue alias: [16][260]
    float*  sqred = reinterpret_cast<float*>(lds + 32768);   // [16][65]
    const int t = threadIdx.x;
    const int l = t & 63, w = t >> 6;
    const int lm = l & 15, q = l >> 4;
    const int i0 = blockIdx.x * 16;

    {
        const int node = t & 15;
        const int g = i0 + node;
        const float* src = (g < NS) ? (support + (size_t)g * IND)
                                    : (query + (size_t)(g - NS) * IND);
#pragma unroll
        for (int i = 0; i < 4; ++i) {
            int cq = (t >> 4) + 16 * i;
            const float* p = src + cq * 8;
            float4 v0 = *reinterpret_cast<const float4*>(p);
            float4 v1 = *reinterpret_cast<const float4*>(p + 4);
            float vv[8] = {v0.x, v0.y, v0.z, v0.w, v1.x, v1.y, v1.z, v1.w};
            bf16x8 h8, l8;
#pragma unroll
            for (int j = 0; j < 8; ++j) {
                unsigned short hu = f2bf(vv[j]);
                float hf = bf2f(hu);
                unsigned short lu = f2bf(vv[j] - hf);
                h8[j] = (short)hu; l8[j] = (short)lu;
            }
            Ehf[cq * 16 + node] = h8;
            Elf[cq * 16 + node] = l8;
        }
    }
    __syncthreads();

    f32x4 acc[4];
#pragma unroll
    for (int nt = 0; nt < 4; ++nt) acc[nt] = (f32x4){0.f, 0.f, 0.f, 0.f};
    const int dimb = 64 * w + lm;
    for (int c = 0; c < 16; ++c) {
        const bf16x8 Anh = Ehf[(c * 4 + q) * 16 + lm];
        const bf16x8 Anl = Elf[(c * 4 + q) * 16 + lm];
        const int fb = c * 1024 + q * 256 + dimb;
#pragma unroll
        for (int nt = 0; nt < 4; ++nt) {
            const bf16x8 Wh = Wthi[fb + 16 * nt];
            const bf16x8 Wl = Wtlo[fb + 16 * nt];
            f32x4 a = acc[nt];
            a = __builtin_amdgcn_mfma_f32_16x16x32_bf16(Anh, Wh, a, 0, 0, 0);
            a = __builtin_amdgcn_mfma_f32_16x16x32_bf16(Anh, Wl, a, 0, 0, 0);
            a = __builtin_amdgcn_mfma_f32_16x16x32_bf16(Anl, Wh, a, 0, 0, 0);
            a = __builtin_amdgcn_mfma_f32_16x16x32_bf16(Anl, Wl, a, 0, 0, 0);
            acc[nt] = a;
        }
    }
    __syncthreads();                             // Ehf/Elf dead -> reuse as E-tile

#pragma unroll
    for (int r = 0; r < 4; ++r) {
        float s = 0.f;
#pragma unroll
        for (int nt = 0; nt < 4; ++nt) {
            float v = acc[nt][r];
            et[(4 * q + r) * 260 + dimb + 16 * nt] = v;
            s += v * v;
        }
        sqred[(4 * q + r) * 65 + w * 16 + lm] = s;
    }
    __syncthreads();

#pragma unroll
    for (int i = 0; i < 2; ++i) {
        int f = t + 256 * i;                     // 0..511 = 8 cd x 4 qd x 16 nodes
        int node = f & 15, qd = (f >> 4) & 3, cd = f >> 6;
        const float* ep = &et[node * 260 + 32 * cd + 8 * qd];
        bf16x8 h8, l8;
#pragma unroll
        for (int j = 0; j < 8; ++j) {
            float v = ep[j];
            unsigned short hu = f2bf(v);
            float hf = bf2f(hu);
            unsigned short lu = f2bf(v - hf);
            h8[j] = (short)hu; l8[j] = (short)lu;
        }
        size_t gi = (size_t)(cd * 4 + qd) * NN + i0 + node;
        Ghi[gi] = h8;
        Glo[gi] = l8;
    }
    if (t < 16) {
        float s = 0.f;
#pragma unroll
        for (int x = 0; x < 64; ++x) s += sqred[t * 65 + x];
        sq[i0 + t] = s;
    }
}

// ---------- 3) fused distance MFMA-GEMM + streaming per-row top-10 ----------
// Structure unchanged from r12 (validated); output now raw u64 keys (cand array)
// so merge_adj skips the float/index repacking.
__global__ __launch_bounds__(256, 2) void dist_topk_kernel(
    const bf16x8* __restrict__ Ghi, const bf16x8* __restrict__ Glo,
    const float* __restrict__ sq, u64* __restrict__ cand)
{
    __shared__ bf16x8 stage[2][1024];            // 2 x 16 KB: [0,512)=hi, [512,1024)=lo; q-major
    __shared__ u64 stk[4][256];                  // 8 KB, slot-major per-thread stacks
    const int t  = threadIdx.x;
    const int l  = t & 63, w = t >> 6;
    const int lm = l & 15, q = l >> 4;
    const int i0 = blockIdx.x * 64;
    const int row = i0 + 16 * w + lm;            // this lane's row
    const int split = blockIdx.y;

    const float  sqi    = sq[row];
    const size_t rowIdx = (size_t)q * NN + row;  // row-frag index within a c-chunk (q-major)

    u64 K[KNB];
#pragma unroll
    for (int s = 0; s < KNB; ++s) K[s] = ~0ull;
    u64 thr = ~0ull;
    int cnt = 0;

    auto drain = [&]() {
        u64 live = __ballot(cnt > 0);
        while (live) {
            if (cnt > 0) {
                --cnt;
                u64 key = stk[cnt][t];
                if (key < thr) {
                    key_insert(key, K);
                    thr = K[KNB - 1];
                }
            }
            live = __ballot(cnt > 0);
        }
    };

    auto stage_issue = [&](int it, int b) {
        const int jt = split * 8 + (it >> 3);
        const int c  = it & 7;
        const int j0 = jt * 128;
        const size_t cbase = (size_t)c * (NN * 4);
        const bool hi = (w < 2);
        const int  wf = (w & 1) * 256;           // frag offset within hi/lo half
        const bf16x8* gsel = hi ? Ghi : Glo;
#pragma unroll
        for (int u = 0; u < 4; ++u) {
            const int f  = wf + u * 64;
            const int qr = f >> 7, col0 = f & 127;
            const bf16x8* g = gsel + cbase + (size_t)qr * NN + j0 + col0 + l;
            __builtin_amdgcn_global_load_lds((const AS1 void*)g,
                                             (AS3 void*)&stage[b][(hi ? 0 : 512) + f],
                                             16, 0, 0);
        }
    };

    stage_issue(0, 0);
    __syncthreads();                             // drains vmcnt -> stage 0 resident

    f32x4 acc[8];
    for (int it = 0; it < 64; ++it) {
        const int c = it & 7;
        const int b = it & 1;
        if (it + 1 < 64) stage_issue(it + 1, (it + 1) & 1);
        if (c == 0) {
#pragma unroll
            for (int mt = 0; mt < 8; ++mt) acc[mt] = (f32x4){0.f, 0.f, 0.f, 0.f};
        }
        const size_t co = (size_t)c * (NN * 4);
        const bf16x8 Bh = Ghi[co + rowIdx];      // row frags: tiny working set, L1/L2-hit
        const bf16x8 Bl = Glo[co + rowIdx];
        const bf16x8* sh = &stage[b][0];
        const bf16x8* sl = &stage[b][512];
        const int fq = q * 128 + lm;             // q-major frag base for this lane
#pragma unroll
        for (int mt = 0; mt < 8; ++mt) {
            const int fi = fq + 16 * mt;
            const bf16x8 Ah = sh[fi];
            const bf16x8 Al = sl[fi];
            f32x4 a = acc[mt];
            a = __builtin_amdgcn_mfma_f32_16x16x32_bf16(Ah, Bh, a, 0, 0, 0);
            a = __builtin_amdgcn_mfma_f32_16x16x32_bf16(Ah, Bl, a, 0, 0, 0);
            a = __builtin_amdgcn_mfma_f32_16x16x32_bf16(Al, Bh, a, 0, 0, 0);
            a = __builtin_amdgcn_mfma_f32_16x16x32_bf16(Al, Bl, a, 0, 0, 0);
            acc[mt] = a;
        }
        if (c == 7) {
            const int j0 = split * 1024 + (it >> 3) * 128;
#pragma unroll
            for (int mt = 0; mt < 8; ++mt) {
                const int jb = j0 + 16 * mt + 4 * q;
                const f32x4 sqj = *reinterpret_cast<const f32x4*>(&sq[jb]);
#pragma unroll
                for (int r = 0; r < 4; ++r) {
                    float d2 = fmaxf(sqi + sqj[r] - 2.0f * acc[mt][r], 0.0f);
                    u64 key = ((u64)__float_as_uint(d2) << 32) | (unsigned)(jb + r);
                    if (key < thr) { stk[cnt][t] = key; ++cnt; }   // cnt <= 3 (depth 4)
                }
                drain();
            }
        }
        __syncthreads();   // consumers done with buf b; stage of it+1 drained (vmcnt)
    }
    // cross-q merge: dump region aliases other waves' stacks -> barrier first (r9 bug)
    __syncthreads();
    u64* dump = reinterpret_cast<u64*>(&stage[0][0]);    // 256*10*8 B = 20480 <= 32768
#pragma unroll
    for (int s = 0; s < KNB; ++s) dump[t * KNB + s] = K[s];
    if (q == 0) {
#pragma unroll
        for (int qq = 1; qq < 4; ++qq)
#pragma unroll
            for (int s = 0; s < KNB; ++s) {
                u64 key = dump[(t + qq * 16) * KNB + s];
                if (key < thr) {
                    key_insert(key, K);
                    thr = K[KNB - 1];
                }
            }
        size_t base = (size_t)row * (NSPLIT * KNB) + split * KNB;
#pragma unroll
        for (int s = 0; s < KNB; ++s) cand[base + s] = K[s];
    }
}

// ---------- 4) merge u64 partial lists -> global top-10, build adjacency bitset ----------
// Split-0's 10 keys are already sorted ascending -> direct init; remaining 70 pass
// a 2-op guard (key < thr) before the branchless insert.
__global__ __launch_bounds__(256) void merge_adj_kernel(
    const u64* __restrict__ cand, unsigned int* __restrict__ bits)
{
    int i = blockIdx.x * blockDim.x + threadIdx.x;
    if (i >= NN) return;
    const u64* cp = cand + (size_t)i * (NSPLIT * KNB);
    u64 K[KNB];
#pragma unroll
    for (int s = 0; s < KNB; ++s) K[s] = cp[s];
    u64 thr = K[KNB - 1];
    for (int s = KNB; s < NSPLIT * KNB; ++s) {
        u64 key = cp[s];
        if (key < thr) { key_insert(key, K); thr = K[KNB - 1]; }
    }
#pragma unroll
    for (int s = 0; s < KNB; ++s) {
        int j = (int)(K[s] & 0xFFFFFFFFu);
        atomicOr(&bits[(size_t)i * 256 + (j >> 5)], 1u << (j & 31));
        atomicOr(&bits[(size_t)j * 256 + (i >> 5)], 1u << (i & 31));
    }
}

// shared edge-list build: ordered (ascending j) per-node LDS list via shuffle prefix scan
__device__ __forceinline__ int build_list(const unsigned int* __restrict__ row,
                                          int c, int* __restrict__ lst)
{
    unsigned int mw[4];
#pragma unroll
    for (int k = 0; k < 4; ++k) mw[k] = row[4 * c + k];
    int cnt = __popc(mw[0]) + __popc(mw[1]) + __popc(mw[2]) + __popc(mw[3]);
    int incl = cnt;
#pragma unroll
    for (int d = 1; d < 64; d <<= 1) {
        int nb = __shfl_up(incl, d, 64);
        if (c >= d) incl += nb;
    }
    const int off = incl - cnt;
    const int deg = __shfl(incl, 63, 64);
    if (deg <= PCAP) {
        int p = off;
#pragma unroll
        for (int k = 0; k < 4; ++k) {
            unsigned int m = mw[k];
            while (m) {
                int b = __ffs(m) - 1;
                m &= m - 1;
                lst[p++] = (4 * c + k) * 32 + b;
            }
        }
    }
    return deg;
}

// ---------- 6a) prop step 1 (labels_init fused): lin[j] = onehot(slab[j]) for j<NS else 0.
// acc += tinv * val adds the exact same fp32 values in the same ascending-j order
// as the previous labels_init + gather -> bitwise identical.
__global__ __launch_bounds__(256) void prop_init_kernel(
    const unsigned int* __restrict__ bits, const int* __restrict__ slab,
    float* __restrict__ lout)
{
    __shared__ int lists[4][PCAP];
    const int grp = threadIdx.x >> 6;
    const int c   = threadIdx.x & 63;
    const int i   = blockIdx.x * 4 + grp;
    const unsigned int* row = bits + (size_t)i * 256;
    const int deg = build_list(row, c, lists[grp]);
    __syncthreads();
    const float tinv = 1.0f / (float)deg;
    float acc = 0.f;
    if (deg <= PCAP) {
        const int* lst = lists[grp];
        for (int d = 0; d < deg; ++d) {
            int j = lst[d];
            float v = (j < NS && slab[j] == c) ? 1.0f : 0.0f;
            acc += __fmul_rn(tinv, v);
        }
    } else {
        for (int w2 = 0; w2 < 256; ++w2) {
            unsigned int m = row[w2];
            while (m) {
                int b = __ffs(m) - 1; m &= m - 1;
                int j = w2 * 32 + b;
                float v = (j < NS && slab[j] == c) ? 1.0f : 0.0f;
                acc += __fmul_rn(tinv, v);
            }
        }
    }
    lout[(size_t)i * 64 + c] = acc;
}

// ---------- 6b) prop step 2 (dense gather, as r13) ----------
__global__ __launch_bounds__(256) void prop_kernel(
    const unsigned int* __restrict__ bits, const float* __restrict__ lin,
    float* __restrict__ lout)
{
    __shared__ int lists[4][PCAP];
    const int grp = threadIdx.x >> 6;
    const int c   = threadIdx.x & 63;
    const int i   = blockIdx.x * 4 + grp;
    const unsigned int* row = bits + (size_t)i * 256;
    const int deg = build_list(row, c, lists[grp]);
    __syncthreads();
    const float tinv = 1.0f / (float)deg;
    float acc = 0.f;
    if (deg <= PCAP) {
        const int* lst = lists[grp];
        int d = 0;
        for (; d + 4 <= deg; d += 4) {
            int j0 = lst[d], j1 = lst[d + 1], j2 = lst[d + 2], j3 = lst[d + 3];
            float x0 = lin[(size_t)j0 * 64 + c];
            float x1 = lin[(size_t)j1 * 64 + c];
            float x2 = lin[(size_t)j2 * 64 + c];
            float x3 = lin[(size_t)j3 * 64 + c];
            acc += __fmul_rn(tinv, x0);
            acc += __fmul_rn(tinv, x1);
            acc += __fmul_rn(tinv, x2);
            acc += __fmul_rn(tinv, x3);
        }
        for (; d < deg; ++d) {
            int j = lst[d];
            acc += __fmul_rn(tinv, lin[(size_t)j * 64 + c]);
        }
    } else {
        for (int w2 = 0; w2 < 256; ++w2) {
            unsigned int m = row[w2];
            while (m) {
                int b = __ffs(m) - 1; m &= m - 1;
                int j = w2 * 32 + b;
                acc += __fmul_rn(tinv, lin[(size_t)j * 64 + c]);
            }
        }
    }
    lout[(size_t)i * 64 + c] = acc;
}

// ---------- 6c) prop step 3 + argmax fused: QUERY ROWS ONLY -> one-hot out ----------
// acc computed exactly as prop_kernel would for row i = NS + q; argmax reduction
// identical to the previous argmax_kernel (first-index tie-break).
__global__ __launch_bounds__(256) void prop_argmax_kernel(
    const unsigned int* __restrict__ bits, const float* __restrict__ lin,
    float* __restrict__ out)
{
    __shared__ int lists[4][PCAP];
    const int grp = threadIdx.x >> 6;
    const int c   = threadIdx.x & 63;
    const int qn  = blockIdx.x * 4 + grp;          // query index 0..NQ-1
    const int i   = NS + qn;
    const unsigned int* row = bits + (size_t)i * 256;
    const int deg = build_list(row, c, lists[grp]);
    __syncthreads();
    const float tinv = 1.0f / (float)deg;
    float acc = 0.f;
    if (deg <= PCAP) {
        const int* lst = lists[grp];
        int d = 0;
        for (; d + 4 <= deg; d += 4) {
            int j0 = lst[d], j1 = lst[d + 1], j2 = lst[d + 2], j3 = lst[d + 3];
            float x0 = lin[(size_t)j0 * 64 + c];
            float x1 = lin[(size_t)j1 * 64 + c];
            float x2 = lin[(size_t)j2 * 64 + c];
            float x3 = lin[(size_t)j3 * 64 + c];
            acc += __fmul_rn(tinv, x0);
            acc += __fmul_rn(tinv, x1);
            acc += __fmul_rn(tinv, x2);
            acc += __fmul_rn(tinv, x3);
        }
        for (; d < deg; ++d) {
            int j = lst[d];
            acc += __fmul_rn(tinv, lin[(size_t)j * 64 + c]);
        }
    } else {
        for (int w2 = 0; w2 < 256; ++w2) {
            unsigned int m = row[w2];
            while (m) {
                int b = __ffs(m) - 1; m &= m - 1;
                int j = w2 * 32 + b;
                acc += __fmul_rn(tinv, lin[(size_t)j * 64 + c]);
            }
        }
    }
    // wave argmax (first-index tie-break), then one-hot write
    float bv = acc; int bi = c;
#pragma unroll
    for (int off = 32; off >= 1; off >>= 1) {
        float ov = __shfl_xor(bv, off, 64);
        int   oi = __shfl_xor(bi, off, 64);
        if (ov > bv || (ov == bv && oi < bi)) { bv = ov; bi = oi; }
    }
    out[(size_t)qn * 64 + c] = (c == bi) ? 1.0f : 0.0f;
}

// ---------- launch ----------
extern "C" void kernel_launch(void* const* d_in, const int* in_sizes, int n_in,
                              void* d_out, int out_size, void* d_ws, size_t ws_size,
                              hipStream_t stream)
{
    const float* support = (const float*)d_in[0];
    const float* query   = (const float*)d_in[1];
    const int*   slab    = (const int*)d_in[2];
    const float* W       = (const float*)d_in[3];
    float* out = (float*)d_out;
    char*  ws  = (char*)d_ws;

    // workspace (phase-aliased), total 13,664,256 B:
    //   [0, 4M)      Ghi  -> bits [0,8M) after dist
    //   [4M, 8M)     Glo
    //   [8M, +32K)   sq (live through dist)
    //   [CV_OFF ...) Wthi/Wtlo (wpack->embed, 512 KB) / cand u64 (dist->merge,
    //                5.24 MB) / la (prop) ; lb at CI_OFF (prop)
    const size_t GHI_OFF = 0;
    const size_t GLO_OFF = 4194304;
    const size_t SQ_OFF  = 8388608;
    const size_t CV_OFF  = 8421376;
    const size_t CI_OFF  = CV_OFF + (size_t)NN * NSPLIT * KNB * 4;   // +2,621,440

    bf16x8*       Ghi  = (bf16x8*)(ws + GHI_OFF);
    bf16x8*       Glo  = (bf16x8*)(ws + GLO_OFF);
    unsigned int* bits = (unsigned int*)(ws + GHI_OFF);   // aliases Ghi/Glo (dead after dist)
    float*        sq   = (float*)(ws + SQ_OFF);
    bf16x8*       Wthi = (bf16x8*)(ws + CV_OFF);          // dead before dist writes cand
    bf16x8*       Wtlo = (bf16x8*)(ws + CV_OFF + 262144);
    u64*          cand = (u64*)  (ws + CV_OFF);           // 8192 x 80 u64 = 5,242,880 B
    float*        la   = (float*)(ws + CV_OFF);           // aliases cand (dead after merge)
    float*        lb   = (float*)(ws + CI_OFF);

    wpack_kernel<<<64, 256, 0, stream>>>(W, Wthi, Wtlo);
    embed_kernel<<<512, 256, 0, stream>>>(support, query, Wthi, Wtlo, Ghi, Glo, sq);
    dist_topk_kernel<<<dim3(128, NSPLIT), 256, 0, stream>>>(Ghi, Glo, sq, cand);
    hipMemsetAsync(bits, 0, (size_t)NN * 256 * sizeof(unsigned int), stream);   // Ghi/Glo dead
    merge_adj_kernel<<<NN / 256, 256, 0, stream>>>(cand, bits);
    prop_init_kernel<<<NN / 4, 256, 0, stream>>>(bits, slab, lb);               // cand dead
    prop_kernel<<<NN / 4, 256, 0, stream>>>(bits, lb, la);
    prop_argmax_kernel<<<NQ / 4, 256, 0, stream>>>(bits, la, out);
}